// Round 16
// baseline (745.423 us; speedup 1.0000x reference)
//
#include <hip/hip_runtime.h>
#include <hip/hip_bf16.h>
#include <math.h>

#define NB 32
#define CK 512
#define C1 1024
#define CA 80
#define CQ 80
#define CQ2 160
#define TEN 400
#define TDE 2000
#define KDIM 1536
#define TPAD 448
#define TQP 2048

static constexpr float TEMP = 0.0005f;

typedef __attribute__((ext_vector_type(8))) short short8;
typedef __attribute__((ext_vector_type(4))) float f32x4;

__device__ inline short f2bf(float v) {
  __hip_bfloat16 h = __float2bfloat16(v);
  return *(short*)&h;
}

// ---------------------------------------------------------------------------
// Prepass: w1 f32[1024][1536] -> bf16
// ---------------------------------------------------------------------------
__global__ __launch_bounds__(256) void cvt_w1_kernel(
    const float* __restrict__ w1, short* __restrict__ w1bf) {
  int i = blockIdx.x * 256 + threadIdx.x;
  if (i < C1 * KDIM) w1bf[i] = f2bf(w1[i]);
}

__global__ __launch_bounds__(256) void cvt_pad_kernel(
    const float* __restrict__ src, short* __restrict__ dst,
    int M, int K, int Mp, int Kp) {
  int i = blockIdx.x * 256 + threadIdx.x;
  if (i >= Mp * Kp) return;
  int r = i / Kp, c = i - r * Kp;
  float v = (r < M && c < K) ? src[(size_t)r * K + c] : 0.f;
  dst[i] = f2bf(v);
}

__global__ __launch_bounds__(256) void im2col_kernel(
    const float* __restrict__ keys, short* __restrict__ BmatT) {
  const int t = blockIdx.x;
  const int b = blockIdx.y;
  const int tid = threadIdx.x;
  short* dst = BmatT + ((size_t)b * TPAD + t) * KDIM;
  #pragma unroll
  for (int i = 0; i < 6; ++i) {
    int k = tid + i * 256;
    int ci = k / 3;
    int dk = k - ci * 3;
    int ts = t + dk - 1;
    float v = (ts >= 0 && ts < TEN) ? keys[((size_t)b * CK + ci) * TEN + ts] : 0.f;
    dst[k] = f2bf(v);
  }
}

__global__ __launch_bounds__(256) void im2col_q_kernel(
    const float* __restrict__ queries, short* __restrict__ Bq) {
  const int t = blockIdx.x;
  const int b = blockIdx.y;
  const int k = threadIdx.x;
  float v = 0.f;
  if (t < TDE && k < 240) {
    int ci = k / 3, dk = k - ci * 3, ts = t + dk - 1;
    v = (ts >= 0 && ts < TDE) ? queries[((size_t)b * CQ + ci) * TDE + ts] : 0.f;
  }
  Bq[((size_t)b * TQP + t) * 256 + k] = f2bf(v);
}

// ---------------------------------------------------------------------------
// Key conv1 via MFMA, BK=64 + prefetch. -> k1t[b][t][co] bf16
// ---------------------------------------------------------------------------
__global__ __launch_bounds__(256) void kconv1_mfma_kernel(
    const short* __restrict__ w1bf, const short* __restrict__ BmatT,
    const float* __restrict__ b1, short* __restrict__ k1t) {
  __shared__ short A_lds[4096];      // 64 rows x 64 k, 128 B/row, swizzled
  __shared__ short B_lds[4096];
  const int co0 = blockIdx.x * 64;
  const int t0  = blockIdx.y * 64;
  const int b   = blockIdx.z;
  const int tid = threadIdx.x;
  const int l = tid & 63, w = tid >> 6;
  const int srow = tid >> 2, sbase = tid & 3;   // row 0..63, slot base 0..3

  const short* gA = w1bf + (size_t)(co0 + srow) * KDIM + sbase * 8;
  const short* gB = BmatT + ((size_t)b * TPAD + t0 + srow) * KDIM + sbase * 8;
  int wbyte[2];
  #pragma unroll
  for (int p = 0; p < 2; ++p)
    wbyte[p] = (srow * 128 + (sbase + p * 4) * 16) ^ ((srow & 7) << 4);

  const int kslot = l >> 4;
  const int arow = w * 16 + (l & 15);
  int bbrow[4];
  #pragma unroll
  for (int g = 0; g < 4; ++g) bbrow[g] = g * 16 + (l & 15);

  f32x4 acc[4];
  #pragma unroll
  for (int g = 0; g < 4; ++g) acc[g] = (f32x4){0.f, 0.f, 0.f, 0.f};

  uint4 av[2], bv[2];
  #pragma unroll
  for (int p = 0; p < 2; ++p) {
    av[p] = *(const uint4*)(gA + p * 32);
    bv[p] = *(const uint4*)(gB + p * 32);
  }

  for (int kt = 0; kt < KDIM / 64; ++kt) {     // 24 iterations
    __syncthreads();
    #pragma unroll
    for (int p = 0; p < 2; ++p) {
      *(uint4*)((char*)A_lds + wbyte[p]) = av[p];
      *(uint4*)((char*)B_lds + wbyte[p]) = bv[p];
    }
    __syncthreads();
    uint4 an[2] = {av[0], av[1]}, bn[2] = {bv[0], bv[1]};
    if (kt + 1 < KDIM / 64) {
      #pragma unroll
      for (int p = 0; p < 2; ++p) {
        an[p] = *(const uint4*)(gA + (kt + 1) * 64 + p * 32);
        bn[p] = *(const uint4*)(gB + (kt + 1) * 64 + p * 32);
      }
    }
    #pragma unroll
    for (int kk = 0; kk < 2; ++kk) {
      int abyte = (arow * 128 + kk * 64 + kslot * 16) ^ ((arow & 7) << 4);
      short8 a = *(const short8*)((const char*)A_lds + abyte);
      #pragma unroll
      for (int g = 0; g < 4; ++g) {
        int bbyte = (bbrow[g] * 128 + kk * 64 + kslot * 16) ^ ((bbrow[g] & 7) << 4);
        short8 bb = *(const short8*)((const char*)B_lds + bbyte);
        acc[g] = __builtin_amdgcn_mfma_f32_16x16x32_bf16(a, bb, acc[g], 0, 0, 0);
      }
    }
    #pragma unroll
    for (int p = 0; p < 2; ++p) { av[p] = an[p]; bv[p] = bn[p]; }
  }

  #pragma unroll
  for (int g = 0; g < 4; ++g) {
    int t = t0 + g * 16 + (l & 15);
    if (t < TEN) {
      #pragma unroll
      for (int r = 0; r < 4; ++r) {
        int co = co0 + w * 16 + kslot * 4 + r;
        float v = acc[g][r] + b1[co];
        k1t[((size_t)b * TPAD + t) * C1 + co] = f2bf(v > 0.f ? v : 0.f);
      }
    }
  }
}

// ---------------------------------------------------------------------------
// Generic small GEMM + prefetch. MODE 1: bf16 [b][t][co]; MODE 2: f32 [b][co][t]
// ---------------------------------------------------------------------------
template <int MODE, bool RELU>
__global__ __launch_bounds__(256) void qgemm_kernel(
    const short* __restrict__ A, const short* __restrict__ B,
    const float* __restrict__ bias, void* __restrict__ outv,
    int M, int Kpad, int kiters, int Nvalid, int outCols,
    size_t bBatchStride, size_t outBatchStride, int outLD) {
  __shared__ short A_lds[2048];
  __shared__ short B_lds[2048];
  const int co0 = blockIdx.x * 64;
  const int t0  = blockIdx.y * 64;
  const int b   = blockIdx.z;
  const int tid = threadIdx.x;
  const int l = tid & 63, w = tid >> 6;
  const int srow = tid >> 2, sslot = tid & 3;

  const short* gA = A + (size_t)(co0 + srow) * Kpad + sslot * 8;
  const short* gB = B + (size_t)b * bBatchStride + (size_t)(t0 + srow) * Kpad + sslot * 8;
  const int wbyte = (srow * 64 + sslot * 16) ^ ((srow & 7) << 4);

  const int kslot = l >> 4;
  const int arow = w * 16 + (l & 15);
  const int abyte = (arow * 64 + kslot * 16) ^ ((arow & 7) << 4);
  int bbyte[4];
  #pragma unroll
  for (int g = 0; g < 4; ++g) {
    int brow = g * 16 + (l & 15);
    bbyte[g] = (brow * 64 + kslot * 16) ^ ((brow & 7) << 4);
  }

  f32x4 acc[4];
  #pragma unroll
  for (int g = 0; g < 4; ++g) acc[g] = (f32x4){0.f, 0.f, 0.f, 0.f};

  uint4 av = *(const uint4*)gA;
  uint4 bv = *(const uint4*)gB;
  for (int kt = 0; kt < kiters; ++kt) {
    __syncthreads();
    *(uint4*)((char*)A_lds + wbyte) = av;
    *(uint4*)((char*)B_lds + wbyte) = bv;
    __syncthreads();
    uint4 an = av, bn = bv;
    if (kt + 1 < kiters) {
      an = *(const uint4*)(gA + (kt + 1) * 32);
      bn = *(const uint4*)(gB + (kt + 1) * 32);
    }
    short8 a = *(const short8*)((const char*)A_lds + abyte);
    #pragma unroll
    for (int g = 0; g < 4; ++g) {
      short8 bb = *(const short8*)((const char*)B_lds + bbyte[g]);
      acc[g] = __builtin_amdgcn_mfma_f32_16x16x32_bf16(a, bb, acc[g], 0, 0, 0);
    }
    av = an; bv = bn;
  }

  #pragma unroll
  for (int g = 0; g < 4; ++g) {
    int t = t0 + g * 16 + (l & 15);
    if (t >= Nvalid) continue;
    #pragma unroll
    for (int r = 0; r < 4; ++r) {
      int co = co0 + w * 16 + kslot * 4 + r;
      if (MODE == 1) {
        if (co < outCols) {
          float v = 0.f;
          if (co < M) {
            v = acc[g][r] + bias[co];
            if (RELU) v = v > 0.f ? v : 0.f;
          }
          ((short*)outv)[(size_t)b * outBatchStride + (size_t)t * outLD + co] = f2bf(v);
        }
      } else {
        if (co < M) {
          float v = acc[g][r] + bias[co];
          if (RELU) v = v > 0.f ? v : 0.f;
          ((float*)outv)[(size_t)b * outBatchStride + (size_t)co * outLD + t] = v;
        }
      }
    }
  }
}

// ---------------------------------------------------------------------------
// Attn prep: q3 -> qA bf16 [b][2048][96] + q2 norms; kfeat -> kB + k2
// ---------------------------------------------------------------------------
__global__ __launch_bounds__(256) void prep_attn_q_kernel(
    const float* __restrict__ q3, short* __restrict__ qA,
    float* __restrict__ q2) {
  __shared__ float sm[80][64];
  const int b = blockIdx.y;
  const int t0 = blockIdx.x * 64;
  const int tid = threadIdx.x;
  for (int idx = tid; idx < 80 * 64; idx += 256) {
    int a = idx >> 6, j = idx & 63;
    int t = t0 + j;
    sm[a][j] = (t < TDE) ? q3[((size_t)b * CA + a) * TDE + t] : 0.f;
  }
  __syncthreads();
  if (tid < 64) {
    float ss = 0.f;
    #pragma unroll 8
    for (int a = 0; a < 80; ++a) { float v = sm[a][tid]; ss += v * v; }
    q2[(size_t)b * TQP + t0 + tid] = ss;
  }
  for (int idx = tid; idx < 64 * 96; idx += 256) {
    int j = idx / 96, k = idx - j * 96;
    float v = (k < 80) ? sm[k][j] : 0.f;
    qA[((size_t)b * TQP + t0 + j) * 96 + k] = f2bf(v);
  }
}

__global__ __launch_bounds__(256) void prep_attn_k_kernel(
    const float* __restrict__ kfeat, short* __restrict__ kB,
    float* __restrict__ k2) {
  __shared__ float sm[80][64];
  const int b = blockIdx.y;
  const int s0 = blockIdx.x * 64;
  const int tid = threadIdx.x;
  for (int idx = tid; idx < 80 * 64; idx += 256) {
    int a = idx >> 6, j = idx & 63;
    int s = s0 + j;
    sm[a][j] = (s < TEN) ? kfeat[((size_t)b * CA + a) * TEN + s] : 0.f;
  }
  __syncthreads();
  if (tid < 64) {
    float ss = 0.f;
    #pragma unroll 8
    for (int a = 0; a < 80; ++a) { float v = sm[a][tid]; ss += v * v; }
    k2[(size_t)b * TPAD + s0 + tid] = ss;
  }
  for (int idx = tid; idx < 64 * 96; idx += 256) {
    int j = idx / 96, k = idx - j * 96;
    float v = (k < 80) ? sm[k][j] : 0.f;
    kB[((size_t)b * TPAD + s0 + j) * 96 + k] = f2bf(v);
  }
}

// ---------------------------------------------------------------------------
// FUSED attention: QK^T MFMA + logp epilogue + in-register softmax.
// Block = 64 t-rows x 400 s. Wave w owns t-rows [w*16, w*16+16).
// A staged once (3 k-panels of 64x32); B streamed in 5 s-tiles of 80 rows.
// acc[25] = full 16x400 per wave; sf = st*5+f, s = sf*16 + (l&15).
// ---------------------------------------------------------------------------
__global__ __launch_bounds__(256) void attn_fused_kernel(
    const short* __restrict__ qA, const short* __restrict__ kB,
    const float* __restrict__ q2, const float* __restrict__ k2,
    const int* __restrict__ mask, float* __restrict__ out_attn,
    float* __restrict__ out_logp) {
  __shared__ short A_lds[3][2048];   // 3 panels x (64 rows x 32 k)
  __shared__ short B_lds[3][2560];   // 3 panels x (80 rows x 32 k)
  __shared__ float k2LDS[400];
  __shared__ int mLDS[400];
  const int t0 = blockIdx.x * 64;
  const int b  = blockIdx.y;
  const int tid = threadIdx.x;
  const int l = tid & 63, w = tid >> 6;

  // stage A (64 rows x 96 k) once
  {
    const int arow_s = tid >> 2, aslot = tid & 3;
    const short* gA = qA + ((size_t)b * TQP + t0 + arow_s) * 96 + aslot * 8;
    #pragma unroll
    for (int p = 0; p < 3; ++p) {
      uint4 v = *(const uint4*)(gA + p * 32);
      *(uint4*)((char*)&A_lds[p][0] +
                ((arow_s * 64 + aslot * 16) ^ ((arow_s & 7) << 4))) = v;
    }
  }
  for (int idx = tid; idx < 400; idx += 256) {
    k2LDS[idx] = k2[(size_t)b * TPAD + idx];
    mLDS[idx] = mask[(size_t)b * TEN + idx];
  }

  const int kslot = l >> 4;
  const int arow = w * 16 + (l & 15);
  const int abyte = (arow * 64 + kslot * 16) ^ ((arow & 7) << 4);

  f32x4 acc[25];
  #pragma unroll
  for (int i = 0; i < 25; ++i) acc[i] = (f32x4){0.f, 0.f, 0.f, 0.f};

  __syncthreads();
  #pragma unroll
  for (int st = 0; st < 5; ++st) {
    // stage B s-tile: 80 rows x 96 k = 960 x 16B chunks
    for (int idx = tid; idx < 960; idx += 256) {
      int row = idx / 12, c = idx - row * 12;
      int panel = c >> 2, ps = c & 3;
      uint4 v = *(const uint4*)(kB + ((size_t)b * TPAD + st * 80 + row) * 96 + c * 8);
      *(uint4*)((char*)&B_lds[panel][0] +
                ((row * 64 + ps * 16) ^ ((row & 7) << 4))) = v;
    }
    __syncthreads();
    #pragma unroll
    for (int kt = 0; kt < 3; ++kt) {
      short8 a = *(const short8*)((const char*)&A_lds[kt][0] + abyte);
      #pragma unroll
      for (int f = 0; f < 5; ++f) {
        int brow = f * 16 + (l & 15);
        short8 bb = *(const short8*)((const char*)&B_lds[kt][0] +
                                     ((brow * 64 + kslot * 16) ^ ((brow & 7) << 4)));
        acc[st * 5 + f] =
            __builtin_amdgcn_mfma_f32_16x16x32_bf16(a, bb, acc[st * 5 + f], 0, 0, 0);
      }
    }
    __syncthreads();
  }

  // ---- epilogue: logp + softmax in-register ----
  int trow[4]; float q2v[4];
  #pragma unroll
  for (int r = 0; r < 4; ++r) {
    trow[r] = t0 + w * 16 + kslot * 4 + r;
    q2v[r] = q2[(size_t)b * TQP + trow[r]];
  }
  // lp in place
  #pragma unroll
  for (int sf = 0; sf < 25; ++sf) {
    int s = sf * 16 + (l & 15);
    float k2v = k2LDS[s];
    bool mk = mLDS[s] != 0;
    #pragma unroll
    for (int r = 0; r < 4; ++r) {
      float lp = mk ? (-TEMP) * (q2v[r] + k2v - 2.f * acc[sf][r]) : -INFINITY;
      acc[sf][r] = lp;
    }
  }
  // write logp
  #pragma unroll
  for (int r = 0; r < 4; ++r) {
    if (trow[r] < TDE) {
      float* dst = out_logp + ((size_t)(b * TDE + trow[r])) * TEN + (l & 15);
      #pragma unroll
      for (int sf = 0; sf < 25; ++sf) dst[sf * 16] = acc[sf][r];
    }
  }
  // row max
  float m[4];
  #pragma unroll
  for (int r = 0; r < 4; ++r) m[r] = -INFINITY;
  #pragma unroll
  for (int sf = 0; sf < 25; ++sf)
    #pragma unroll
    for (int r = 0; r < 4; ++r) m[r] = fmaxf(m[r], acc[sf][r]);
  #pragma unroll
  for (int o = 1; o < 16; o <<= 1)
    #pragma unroll
    for (int r = 0; r < 4; ++r) m[r] = fmaxf(m[r], __shfl_xor(m[r], o, 64));
  // exp + sum (in place)
  float sum[4] = {0.f, 0.f, 0.f, 0.f};
  #pragma unroll
  for (int sf = 0; sf < 25; ++sf)
    #pragma unroll
    for (int r = 0; r < 4; ++r) {
      float v = acc[sf][r];
      float e = (v != -INFINITY) ? __expf(v - m[r]) : 0.f;
      acc[sf][r] = e;
      sum[r] += e;
    }
  #pragma unroll
  for (int o = 1; o < 16; o <<= 1)
    #pragma unroll
    for (int r = 0; r < 4; ++r) sum[r] += __shfl_xor(sum[r], o, 64);
  float inv[4];
  #pragma unroll
  for (int r = 0; r < 4; ++r) inv[r] = 1.0f / sum[r];
  // write attn
  #pragma unroll
  for (int r = 0; r < 4; ++r) {
    if (trow[r] < TDE) {
      float* dst = out_attn + ((size_t)(b * TDE + trow[r])) * TEN + (l & 15);
      #pragma unroll
      for (int sf = 0; sf < 25; ++sf) dst[sf * 16] = acc[sf][r] * inv[r];
    }
  }
}

extern "C" void kernel_launch(void* const* d_in, const int* in_sizes, int n_in,
                              void* d_out, int out_size, void* d_ws, size_t ws_size,
                              hipStream_t stream) {
  const float* queries = (const float*)d_in[0];
  const float* keys    = (const float*)d_in[1];
  const int*   mask    = (const int*)d_in[2];
  const float* kw1 = (const float*)d_in[3];
  const float* kb1 = (const float*)d_in[4];
  const float* kw2 = (const float*)d_in[5];
  const float* kb2 = (const float*)d_in[6];
  const float* qw1 = (const float*)d_in[7];
  const float* qb1 = (const float*)d_in[8];
  const float* qw2 = (const float*)d_in[9];
  const float* qb2 = (const float*)d_in[10];
  const float* qw3 = (const float*)d_in[11];
  const float* qb3 = (const float*)d_in[12];
  float* out = (float*)d_out;

  char* ws = (char*)d_ws;
  short* BmatT = (short*)ws;
  short* w1bf  = (short*)(ws + 44040192);
  short* k1t   = (short*)(ws + 47185920);
  short* w2bf  = (short*)(ws + 76546048);
  short* w1q   = (short*)(ws + 76808192);
  short* w2q   = (short*)(ws + 76906496);
  short* w3q   = (short*)(ws + 76947456);
  short* Bq    = (short*)ws;
  short* q1bf  = (short*)(ws + 33554432);
  short* q2bf  = (short*)(ws + 54525952);
  float* q3    = (float*)ws;
  short* qA    = (short*)(ws + 20480000);
  float* q2n   = (float*)(ws + 33062912);
  short* kB    = (short*)(ws + 47185920);
  float* k2n   = (float*)(ws + 49938432);
  float* kfeat = (float*)(ws + 81920000);

  const long long HALF = 25600000LL;
  float* out_attn = out;
  float* out_logp = out + HALF;

  // --- key path (all MFMA) ---
  cvt_w1_kernel<<<dim3((C1 * KDIM + 255) / 256), dim3(256), 0, stream>>>(kw1, w1bf);
  im2col_kernel<<<dim3(TEN, NB), dim3(256), 0, stream>>>(keys, BmatT);
  kconv1_mfma_kernel<<<dim3(16, 7, NB), dim3(256), 0, stream>>>(w1bf, BmatT, kb1, k1t);
  cvt_pad_kernel<<<dim3((128 * 1024 + 255) / 256), dim3(256), 0, stream>>>(
      kw2, w2bf, CA, C1, 128, C1);
  qgemm_kernel<2, false><<<dim3(2, 7, NB), dim3(256), 0, stream>>>(
      w2bf, k1t, kb2, kfeat, CA, C1, 32, TEN, CA,
      (size_t)TPAD * C1, (size_t)CA * TEN, TEN);

  // --- query path (MFMA chain) ---
  cvt_pad_kernel<<<dim3((192 * 256 + 255) / 256), dim3(256), 0, stream>>>(
      qw1, w1q, CQ2, 240, 192, 256);
  cvt_pad_kernel<<<dim3((128 * 160 + 255) / 256), dim3(256), 0, stream>>>(
      qw2, w2q, CA, CQ2, 128, 160);
  cvt_pad_kernel<<<dim3((128 * 96 + 255) / 256), dim3(256), 0, stream>>>(
      qw3, w3q, CA, CQ, 128, 96);
  im2col_q_kernel<<<dim3(TQP, NB), dim3(256), 0, stream>>>(queries, Bq);
  qgemm_kernel<1, true><<<dim3(3, TQP / 64, NB), dim3(256), 0, stream>>>(
      w1q, Bq, qb1, q1bf, CQ2, 256, 8, TDE, 160,
      (size_t)TQP * 256, (size_t)TQP * 160, 160);
  qgemm_kernel<1, true><<<dim3(2, TQP / 64, NB), dim3(256), 0, stream>>>(
      w2q, q1bf, qb2, q2bf, CA, 160, 5, TDE, 96,
      (size_t)TQP * 160, (size_t)TQP * 96, 96);
  qgemm_kernel<2, false><<<dim3(2, TQP / 64, NB), dim3(256), 0, stream>>>(
      w3q, q2bf, qb3, q3, CA, 96, 3, TDE, 80,
      (size_t)TQP * 96, (size_t)CA * TDE, TDE);

  // --- attention: prep -> fused QK^T + softmax ---
  prep_attn_q_kernel<<<dim3(TQP / 64, NB), dim3(256), 0, stream>>>(q3, qA, q2n);
  prep_attn_k_kernel<<<dim3(TPAD / 64, NB), dim3(256), 0, stream>>>(kfeat, kB, k2n);
  attn_fused_kernel<<<dim3(TQP / 64, NB), dim3(256), 0, stream>>>(
      qA, kB, q2n, k2n, mask, out_attn, out_logp);
}

// Round 17
// 395.154 us; speedup vs baseline: 1.8864x; 1.8864x over previous
//
#include <hip/hip_runtime.h>
#include <hip/hip_bf16.h>
#include <math.h>

#define NB 32
#define CK 512
#define C1 1024
#define CA 80
#define CQ 80
#define CQ2 160
#define TEN 400
#define TDE 2000
#define KDIM 1536
#define TPAD 448
#define TQP 2048

static constexpr float TEMP = 0.0005f;

typedef __attribute__((ext_vector_type(8))) short short8;
typedef __attribute__((ext_vector_type(4))) float f32x4;

__device__ inline short f2bf(float v) {
  __hip_bfloat16 h = __float2bfloat16(v);
  return *(short*)&h;
}

// ---------------------------------------------------------------------------
// Prepass: w1 f32[1024][1536] -> bf16
// ---------------------------------------------------------------------------
__global__ __launch_bounds__(256) void cvt_w1_kernel(
    const float* __restrict__ w1, short* __restrict__ w1bf) {
  int i = blockIdx.x * 256 + threadIdx.x;
  if (i < C1 * KDIM) w1bf[i] = f2bf(w1[i]);
}

__global__ __launch_bounds__(256) void cvt_pad_kernel(
    const float* __restrict__ src, short* __restrict__ dst,
    int M, int K, int Mp, int Kp) {
  int i = blockIdx.x * 256 + threadIdx.x;
  if (i >= Mp * Kp) return;
  int r = i / Kp, c = i - r * Kp;
  float v = (r < M && c < K) ? src[(size_t)r * K + c] : 0.f;
  dst[i] = f2bf(v);
}

__global__ __launch_bounds__(256) void im2col_kernel(
    const float* __restrict__ keys, short* __restrict__ BmatT) {
  const int t = blockIdx.x;
  const int b = blockIdx.y;
  const int tid = threadIdx.x;
  short* dst = BmatT + ((size_t)b * TPAD + t) * KDIM;
  #pragma unroll
  for (int i = 0; i < 6; ++i) {
    int k = tid + i * 256;
    int ci = k / 3;
    int dk = k - ci * 3;
    int ts = t + dk - 1;
    float v = (ts >= 0 && ts < TEN) ? keys[((size_t)b * CK + ci) * TEN + ts] : 0.f;
    dst[k] = f2bf(v);
  }
}

__global__ __launch_bounds__(256) void im2col_q_kernel(
    const float* __restrict__ queries, short* __restrict__ Bq) {
  const int t = blockIdx.x;
  const int b = blockIdx.y;
  const int k = threadIdx.x;
  float v = 0.f;
  if (t < TDE && k < 240) {
    int ci = k / 3, dk = k - ci * 3, ts = t + dk - 1;
    v = (ts >= 0 && ts < TDE) ? queries[((size_t)b * CQ + ci) * TDE + ts] : 0.f;
  }
  Bq[((size_t)b * TQP + t) * 256 + k] = f2bf(v);
}

// ---------------------------------------------------------------------------
// Key conv1 via MFMA (REVERTED to proven R14/R15: BK=32, no reg-prefetch).
// -> k1t[b][t][co] bf16
// ---------------------------------------------------------------------------
__global__ __launch_bounds__(256) void kconv1_mfma_kernel(
    const short* __restrict__ w1bf, const short* __restrict__ BmatT,
    const float* __restrict__ b1, short* __restrict__ k1t) {
  __shared__ short A_lds[2048];
  __shared__ short B_lds[2048];
  const int co0 = blockIdx.x * 64;
  const int t0  = blockIdx.y * 64;
  const int b   = blockIdx.z;
  const int tid = threadIdx.x;
  const int l = tid & 63, w = tid >> 6;
  const int srow = tid >> 2, sslot = tid & 3;

  const char* gA = (const char*)(w1bf + (size_t)(co0 + srow) * KDIM + sslot * 8);
  const char* gB = (const char*)(BmatT + ((size_t)b * TPAD + t0 + srow) * KDIM + sslot * 8);
  const int wbyte = (srow * 64 + sslot * 16) ^ ((srow & 7) << 4);

  const int kslot = l >> 4;
  const int arow = w * 16 + (l & 15);
  const int abyte = (arow * 64 + kslot * 16) ^ ((arow & 7) << 4);
  int bbyte[4];
  #pragma unroll
  for (int g = 0; g < 4; ++g) {
    int brow = g * 16 + (l & 15);
    bbyte[g] = (brow * 64 + kslot * 16) ^ ((brow & 7) << 4);
  }

  f32x4 acc[4];
  #pragma unroll
  for (int g = 0; g < 4; ++g) acc[g] = (f32x4){0.f, 0.f, 0.f, 0.f};

  for (int kt = 0; kt < KDIM / 32; ++kt) {
    uint4 av = *(const uint4*)(gA + (size_t)kt * 64);
    uint4 bv = *(const uint4*)(gB + (size_t)kt * 64);
    __syncthreads();
    *(uint4*)((char*)A_lds + wbyte) = av;
    *(uint4*)((char*)B_lds + wbyte) = bv;
    __syncthreads();
    short8 a = *(const short8*)((const char*)A_lds + abyte);
    #pragma unroll
    for (int g = 0; g < 4; ++g) {
      short8 bb = *(const short8*)((const char*)B_lds + bbyte[g]);
      acc[g] = __builtin_amdgcn_mfma_f32_16x16x32_bf16(a, bb, acc[g], 0, 0, 0);
    }
  }
  #pragma unroll
  for (int g = 0; g < 4; ++g) {
    int t = t0 + g * 16 + (l & 15);
    if (t < TEN) {
      #pragma unroll
      for (int r = 0; r < 4; ++r) {
        int co = co0 + w * 16 + kslot * 4 + r;
        float v = acc[g][r] + b1[co];
        k1t[((size_t)b * TPAD + t) * C1 + co] = f2bf(v > 0.f ? v : 0.f);
      }
    }
  }
}

// ---------------------------------------------------------------------------
// Generic small GEMM + prefetch (kept from R16 — measured improvement).
// MODE 1: bf16 [b][t][co]; MODE 2: f32 [b][co][t]
// ---------------------------------------------------------------------------
template <int MODE, bool RELU>
__global__ __launch_bounds__(256) void qgemm_kernel(
    const short* __restrict__ A, const short* __restrict__ B,
    const float* __restrict__ bias, void* __restrict__ outv,
    int M, int Kpad, int kiters, int Nvalid, int outCols,
    size_t bBatchStride, size_t outBatchStride, int outLD) {
  __shared__ short A_lds[2048];
  __shared__ short B_lds[2048];
  const int co0 = blockIdx.x * 64;
  const int t0  = blockIdx.y * 64;
  const int b   = blockIdx.z;
  const int tid = threadIdx.x;
  const int l = tid & 63, w = tid >> 6;
  const int srow = tid >> 2, sslot = tid & 3;

  const short* gA = A + (size_t)(co0 + srow) * Kpad + sslot * 8;
  const short* gB = B + (size_t)b * bBatchStride + (size_t)(t0 + srow) * Kpad + sslot * 8;
  const int wbyte = (srow * 64 + sslot * 16) ^ ((srow & 7) << 4);

  const int kslot = l >> 4;
  const int arow = w * 16 + (l & 15);
  const int abyte = (arow * 64 + kslot * 16) ^ ((arow & 7) << 4);
  int bbyte[4];
  #pragma unroll
  for (int g = 0; g < 4; ++g) {
    int brow = g * 16 + (l & 15);
    bbyte[g] = (brow * 64 + kslot * 16) ^ ((brow & 7) << 4);
  }

  f32x4 acc[4];
  #pragma unroll
  for (int g = 0; g < 4; ++g) acc[g] = (f32x4){0.f, 0.f, 0.f, 0.f};

  uint4 av = *(const uint4*)gA;
  uint4 bv = *(const uint4*)gB;
  for (int kt = 0; kt < kiters; ++kt) {
    __syncthreads();
    *(uint4*)((char*)A_lds + wbyte) = av;
    *(uint4*)((char*)B_lds + wbyte) = bv;
    __syncthreads();
    uint4 an = av, bn = bv;
    if (kt + 1 < kiters) {
      an = *(const uint4*)(gA + (kt + 1) * 32);
      bn = *(const uint4*)(gB + (kt + 1) * 32);
    }
    short8 a = *(const short8*)((const char*)A_lds + abyte);
    #pragma unroll
    for (int g = 0; g < 4; ++g) {
      short8 bb = *(const short8*)((const char*)B_lds + bbyte[g]);
      acc[g] = __builtin_amdgcn_mfma_f32_16x16x32_bf16(a, bb, acc[g], 0, 0, 0);
    }
    av = an; bv = bn;
  }

  #pragma unroll
  for (int g = 0; g < 4; ++g) {
    int t = t0 + g * 16 + (l & 15);
    if (t >= Nvalid) continue;
    #pragma unroll
    for (int r = 0; r < 4; ++r) {
      int co = co0 + w * 16 + kslot * 4 + r;
      if (MODE == 1) {
        if (co < outCols) {
          float v = 0.f;
          if (co < M) {
            v = acc[g][r] + bias[co];
            if (RELU) v = v > 0.f ? v : 0.f;
          }
          ((short*)outv)[(size_t)b * outBatchStride + (size_t)t * outLD + co] = f2bf(v);
        }
      } else {
        if (co < M) {
          float v = acc[g][r] + bias[co];
          if (RELU) v = v > 0.f ? v : 0.f;
          ((float*)outv)[(size_t)b * outBatchStride + (size_t)co * outLD + t] = v;
        }
      }
    }
  }
}

// ---------------------------------------------------------------------------
// Attn prep: q3 -> qA bf16 [b][2048][96] + q2 norms; kfeat -> kB + k2
// ---------------------------------------------------------------------------
__global__ __launch_bounds__(256) void prep_attn_q_kernel(
    const float* __restrict__ q3, short* __restrict__ qA,
    float* __restrict__ q2) {
  __shared__ float sm[80][64];
  const int b = blockIdx.y;
  const int t0 = blockIdx.x * 64;
  const int tid = threadIdx.x;
  for (int idx = tid; idx < 80 * 64; idx += 256) {
    int a = idx >> 6, j = idx & 63;
    int t = t0 + j;
    sm[a][j] = (t < TDE) ? q3[((size_t)b * CA + a) * TDE + t] : 0.f;
  }
  __syncthreads();
  if (tid < 64) {
    float ss = 0.f;
    #pragma unroll 8
    for (int a = 0; a < 80; ++a) { float v = sm[a][tid]; ss += v * v; }
    q2[(size_t)b * TQP + t0 + tid] = ss;
  }
  for (int idx = tid; idx < 64 * 96; idx += 256) {
    int j = idx / 96, k = idx - j * 96;
    float v = (k < 80) ? sm[k][j] : 0.f;
    qA[((size_t)b * TQP + t0 + j) * 96 + k] = f2bf(v);
  }
}

__global__ __launch_bounds__(256) void prep_attn_k_kernel(
    const float* __restrict__ kfeat, short* __restrict__ kB,
    float* __restrict__ k2) {
  __shared__ float sm[80][64];
  const int b = blockIdx.y;
  const int s0 = blockIdx.x * 64;
  const int tid = threadIdx.x;
  for (int idx = tid; idx < 80 * 64; idx += 256) {
    int a = idx >> 6, j = idx & 63;
    int s = s0 + j;
    sm[a][j] = (s < TEN) ? kfeat[((size_t)b * CA + a) * TEN + s] : 0.f;
  }
  __syncthreads();
  if (tid < 64) {
    float ss = 0.f;
    #pragma unroll 8
    for (int a = 0; a < 80; ++a) { float v = sm[a][tid]; ss += v * v; }
    k2[(size_t)b * TPAD + s0 + tid] = ss;
  }
  for (int idx = tid; idx < 64 * 96; idx += 256) {
    int j = idx / 96, k = idx - j * 96;
    float v = (k < 80) ? sm[k][j] : 0.f;
    kB[((size_t)b * TPAD + s0 + j) * 96 + k] = f2bf(v);
  }
}

// ---------------------------------------------------------------------------
// FUSED attention (kept from R16): QK^T MFMA + logp + in-register softmax.
// ---------------------------------------------------------------------------
__global__ __launch_bounds__(256) void attn_fused_kernel(
    const short* __restrict__ qA, const short* __restrict__ kB,
    const float* __restrict__ q2, const float* __restrict__ k2,
    const int* __restrict__ mask, float* __restrict__ out_attn,
    float* __restrict__ out_logp) {
  __shared__ short A_lds[3][2048];
  __shared__ short B_lds[3][2560];
  __shared__ float k2LDS[400];
  __shared__ int mLDS[400];
  const int t0 = blockIdx.x * 64;
  const int b  = blockIdx.y;
  const int tid = threadIdx.x;
  const int l = tid & 63, w = tid >> 6;

  {
    const int arow_s = tid >> 2, aslot = tid & 3;
    const short* gA = qA + ((size_t)b * TQP + t0 + arow_s) * 96 + aslot * 8;
    #pragma unroll
    for (int p = 0; p < 3; ++p) {
      uint4 v = *(const uint4*)(gA + p * 32);
      *(uint4*)((char*)&A_lds[p][0] +
                ((arow_s * 64 + aslot * 16) ^ ((arow_s & 7) << 4))) = v;
    }
  }
  for (int idx = tid; idx < 400; idx += 256) {
    k2LDS[idx] = k2[(size_t)b * TPAD + idx];
    mLDS[idx] = mask[(size_t)b * TEN + idx];
  }

  const int kslot = l >> 4;
  const int arow = w * 16 + (l & 15);
  const int abyte = (arow * 64 + kslot * 16) ^ ((arow & 7) << 4);

  f32x4 acc[25];
  #pragma unroll
  for (int i = 0; i < 25; ++i) acc[i] = (f32x4){0.f, 0.f, 0.f, 0.f};

  __syncthreads();
  #pragma unroll
  for (int st = 0; st < 5; ++st) {
    for (int idx = tid; idx < 960; idx += 256) {
      int row = idx / 12, c = idx - row * 12;
      int panel = c >> 2, ps = c & 3;
      uint4 v = *(const uint4*)(kB + ((size_t)b * TPAD + st * 80 + row) * 96 + c * 8);
      *(uint4*)((char*)&B_lds[panel][0] +
                ((row * 64 + ps * 16) ^ ((row & 7) << 4))) = v;
    }
    __syncthreads();
    #pragma unroll
    for (int kt = 0; kt < 3; ++kt) {
      short8 a = *(const short8*)((const char*)&A_lds[kt][0] + abyte);
      #pragma unroll
      for (int f = 0; f < 5; ++f) {
        int brow = f * 16 + (l & 15);
        short8 bb = *(const short8*)((const char*)&B_lds[kt][0] +
                                     ((brow * 64 + kslot * 16) ^ ((brow & 7) << 4)));
        acc[st * 5 + f] =
            __builtin_amdgcn_mfma_f32_16x16x32_bf16(a, bb, acc[st * 5 + f], 0, 0, 0);
      }
    }
    __syncthreads();
  }

  int trow[4]; float q2v[4];
  #pragma unroll
  for (int r = 0; r < 4; ++r) {
    trow[r] = t0 + w * 16 + kslot * 4 + r;
    q2v[r] = q2[(size_t)b * TQP + trow[r]];
  }
  #pragma unroll
  for (int sf = 0; sf < 25; ++sf) {
    int s = sf * 16 + (l & 15);
    float k2v = k2LDS[s];
    bool mk = mLDS[s] != 0;
    #pragma unroll
    for (int r = 0; r < 4; ++r) {
      float lp = mk ? (-TEMP) * (q2v[r] + k2v - 2.f * acc[sf][r]) : -INFINITY;
      acc[sf][r] = lp;
    }
  }
  #pragma unroll
  for (int r = 0; r < 4; ++r) {
    if (trow[r] < TDE) {
      float* dst = out_logp + ((size_t)(b * TDE + trow[r])) * TEN + (l & 15);
      #pragma unroll
      for (int sf = 0; sf < 25; ++sf) dst[sf * 16] = acc[sf][r];
    }
  }
  float m[4];
  #pragma unroll
  for (int r = 0; r < 4; ++r) m[r] = -INFINITY;
  #pragma unroll
  for (int sf = 0; sf < 25; ++sf)
    #pragma unroll
    for (int r = 0; r < 4; ++r) m[r] = fmaxf(m[r], acc[sf][r]);
  #pragma unroll
  for (int o = 1; o < 16; o <<= 1)
    #pragma unroll
    for (int r = 0; r < 4; ++r) m[r] = fmaxf(m[r], __shfl_xor(m[r], o, 64));
  float sum[4] = {0.f, 0.f, 0.f, 0.f};
  #pragma unroll
  for (int sf = 0; sf < 25; ++sf)
    #pragma unroll
    for (int r = 0; r < 4; ++r) {
      float v = acc[sf][r];
      float e = (v != -INFINITY) ? __expf(v - m[r]) : 0.f;
      acc[sf][r] = e;
      sum[r] += e;
    }
  #pragma unroll
  for (int o = 1; o < 16; o <<= 1)
    #pragma unroll
    for (int r = 0; r < 4; ++r) sum[r] += __shfl_xor(sum[r], o, 64);
  float inv[4];
  #pragma unroll
  for (int r = 0; r < 4; ++r) inv[r] = 1.0f / sum[r];
  #pragma unroll
  for (int r = 0; r < 4; ++r) {
    if (trow[r] < TDE) {
      float* dst = out_attn + ((size_t)(b * TDE + trow[r])) * TEN + (l & 15);
      #pragma unroll
      for (int sf = 0; sf < 25; ++sf) dst[sf * 16] = acc[sf][r] * inv[r];
    }
  }
}

extern "C" void kernel_launch(void* const* d_in, const int* in_sizes, int n_in,
                              void* d_out, int out_size, void* d_ws, size_t ws_size,
                              hipStream_t stream) {
  const float* queries = (const float*)d_in[0];
  const float* keys    = (const float*)d_in[1];
  const int*   mask    = (const int*)d_in[2];
  const float* kw1 = (const float*)d_in[3];
  const float* kb1 = (const float*)d_in[4];
  const float* kw2 = (const float*)d_in[5];
  const float* kb2 = (const float*)d_in[6];
  const float* qw1 = (const float*)d_in[7];
  const float* qb1 = (const float*)d_in[8];
  const float* qw2 = (const float*)d_in[9];
  const float* qb2 = (const float*)d_in[10];
  const float* qw3 = (const float*)d_in[11];
  const float* qb3 = (const float*)d_in[12];
  float* out = (float*)d_out;

  char* ws = (char*)d_ws;
  short* BmatT = (short*)ws;
  short* w1bf  = (short*)(ws + 44040192);
  short* k1t   = (short*)(ws + 47185920);
  short* w2bf  = (short*)(ws + 76546048);
  short* w1q   = (short*)(ws + 76808192);
  short* w2q   = (short*)(ws + 76906496);
  short* w3q   = (short*)(ws + 76947456);
  short* Bq    = (short*)ws;
  short* q1bf  = (short*)(ws + 33554432);
  short* q2bf  = (short*)(ws + 54525952);
  float* q3    = (float*)ws;
  short* qA    = (short*)(ws + 20480000);
  float* q2n   = (float*)(ws + 33062912);
  short* kB    = (short*)(ws + 47185920);
  float* k2n   = (float*)(ws + 49938432);
  float* kfeat = (float*)(ws + 81920000);

  const long long HALF = 25600000LL;
  float* out_attn = out;
  float* out_logp = out + HALF;

  // --- key path (all MFMA) ---
  cvt_w1_kernel<<<dim3((C1 * KDIM + 255) / 256), dim3(256), 0, stream>>>(kw1, w1bf);
  im2col_kernel<<<dim3(TEN, NB), dim3(256), 0, stream>>>(keys, BmatT);
  kconv1_mfma_kernel<<<dim3(16, 7, NB), dim3(256), 0, stream>>>(w1bf, BmatT, kb1, k1t);
  cvt_pad_kernel<<<dim3((128 * 1024 + 255) / 256), dim3(256), 0, stream>>>(
      kw2, w2bf, CA, C1, 128, C1);
  qgemm_kernel<2, false><<<dim3(2, 7, NB), dim3(256), 0, stream>>>(
      w2bf, k1t, kb2, kfeat, CA, C1, 32, TEN, CA,
      (size_t)TPAD * C1, (size_t)CA * TEN, TEN);

  // --- query path (MFMA chain) ---
  cvt_pad_kernel<<<dim3((192 * 256 + 255) / 256), dim3(256), 0, stream>>>(
      qw1, w1q, CQ2, 240, 192, 256);
  cvt_pad_kernel<<<dim3((128 * 160 + 255) / 256), dim3(256), 0, stream>>>(
      qw2, w2q, CA, CQ2, 128, 160);
  cvt_pad_kernel<<<dim3((128 * 96 + 255) / 256), dim3(256), 0, stream>>>(
      qw3, w3q, CA, CQ, 128, 96);
  im2col_q_kernel<<<dim3(TQP, NB), dim3(256), 0, stream>>>(queries, Bq);
  qgemm_kernel<1, true><<<dim3(3, TQP / 64, NB), dim3(256), 0, stream>>>(
      w1q, Bq, qb1, q1bf, CQ2, 256, 8, TDE, 160,
      (size_t)TQP * 256, (size_t)TQP * 160, 160);
  qgemm_kernel<1, true><<<dim3(2, TQP / 64, NB), dim3(256), 0, stream>>>(
      w2q, q1bf, qb2, q2bf, CA, 160, 5, TDE, 96,
      (size_t)TQP * 160, (size_t)TQP * 96, 96);
  qgemm_kernel<2, false><<<dim3(2, TQP / 64, NB), dim3(256), 0, stream>>>(
      w3q, q2bf, qb3, q3, CA, 96, 3, TDE, 80,
      (size_t)TQP * 96, (size_t)CA * TDE, TDE);

  // --- attention: prep -> fused QK^T + softmax ---
  prep_attn_q_kernel<<<dim3(TQP / 64, NB), dim3(256), 0, stream>>>(q3, qA, q2n);
  prep_attn_k_kernel<<<dim3(TPAD / 64, NB), dim3(256), 0, stream>>>(kfeat, kB, k2n);
  attn_fused_kernel<<<dim3(TQP / 64, NB), dim3(256), 0, stream>>>(
      qA, kB, q2n, k2n, mask, out_attn, out_logp);
}

// Round 18
// 379.961 us; speedup vs baseline: 1.9618x; 1.0400x over previous
//
#include <hip/hip_runtime.h>
#include <hip/hip_bf16.h>
#include <math.h>

#define NB 32
#define CK 512
#define C1 1024
#define CA 80
#define CQ 80
#define CQ2 160
#define TEN 400
#define TDE 2000
#define KDIM 1536
#define TPAD 448
#define TQP 2048

static constexpr float TEMP = 0.0005f;

typedef __attribute__((ext_vector_type(8))) short short8;
typedef __attribute__((ext_vector_type(4))) float f32x4;

__device__ inline short f2bf(float v) {
  __hip_bfloat16 h = __float2bfloat16(v);
  return *(short*)&h;
}

__device__ inline void gload_lds16(const void* g, void* l) {
  __builtin_amdgcn_global_load_lds(
      (const __attribute__((address_space(1))) unsigned int*)g,
      (__attribute__((address_space(3))) unsigned int*)l, 16, 0, 0);
}

// ---------------------------------------------------------------------------
// Prepass: w1 f32[1024][1536] -> bf16
// ---------------------------------------------------------------------------
__global__ __launch_bounds__(256) void cvt_w1_kernel(
    const float* __restrict__ w1, short* __restrict__ w1bf) {
  int i = blockIdx.x * 256 + threadIdx.x;
  if (i < C1 * KDIM) w1bf[i] = f2bf(w1[i]);
}

__global__ __launch_bounds__(256) void cvt_pad_kernel(
    const float* __restrict__ src, short* __restrict__ dst,
    int M, int K, int Mp, int Kp) {
  int i = blockIdx.x * 256 + threadIdx.x;
  if (i >= Mp * Kp) return;
  int r = i / Kp, c = i - r * Kp;
  float v = (r < M && c < K) ? src[(size_t)r * K + c] : 0.f;
  dst[i] = f2bf(v);
}

__global__ __launch_bounds__(256) void im2col_kernel(
    const float* __restrict__ keys, short* __restrict__ BmatT) {
  const int t = blockIdx.x;
  const int b = blockIdx.y;
  const int tid = threadIdx.x;
  short* dst = BmatT + ((size_t)b * TPAD + t) * KDIM;
  #pragma unroll
  for (int i = 0; i < 6; ++i) {
    int k = tid + i * 256;
    int ci = k / 3;
    int dk = k - ci * 3;
    int ts = t + dk - 1;
    float v = (ts >= 0 && ts < TEN) ? keys[((size_t)b * CK + ci) * TEN + ts] : 0.f;
    dst[k] = f2bf(v);
  }
}

__global__ __launch_bounds__(256) void im2col_q_kernel(
    const float* __restrict__ queries, short* __restrict__ Bq) {
  const int t = blockIdx.x;
  const int b = blockIdx.y;
  const int k = threadIdx.x;
  float v = 0.f;
  if (t < TDE && k < 240) {
    int ci = k / 3, dk = k - ci * 3, ts = t + dk - 1;
    v = (ts >= 0 && ts < TDE) ? queries[((size_t)b * CQ + ci) * TDE + ts] : 0.f;
  }
  Bq[((size_t)b * TQP + t) * 256 + k] = f2bf(v);
}

// ---------------------------------------------------------------------------
// Key conv1 via MFMA v3: 128co x 64t tile, global_load_lds(16B) staging.
// LDS stays LINEAR; global SOURCE is inverse-swizzled; reads apply the
// forward swizzle (rule #21: both-sides-or-neither). -> k1t[b][t][co] bf16
// ---------------------------------------------------------------------------
__global__ __launch_bounds__(256) void kconv1_mfma_kernel(
    const short* __restrict__ w1bf, const short* __restrict__ BmatT,
    const float* __restrict__ b1, short* __restrict__ k1t) {
  __shared__ short A_lds[4096];   // 128 rows x 32 k (8 KB)
  __shared__ short B_lds[2048];   // 64 rows x 32 k (4 KB)
  const int co0 = blockIdx.x * 128;
  const int t0  = blockIdx.y * 64;
  const int b   = blockIdx.z;
  const int tid = threadIdx.x;
  const int l = tid & 63, w = tid >> 6;

  // inverse of Y = X ^ (((X>>6)&7)<<4)
  auto invswz = [](int Y) {
    int X = Y;
    X ^= ((Y >> 8) & 1) << 6;
    X ^= ((Y >> 7) & 1) << 5;
    X ^= (((Y >> 6) ^ (Y >> 8)) & 1) << 4;
    return X;
  };

  // A: 8 KB = 8 calls of 1024B; wave w does calls w*2, w*2+1.
  const short* gA[2];
  #pragma unroll
  for (int c = 0; c < 2; ++c) {
    int Y = (w * 2 + c) * 1024 + l * 16;
    int X = invswz(Y);
    int row = X >> 6, slot = (X >> 4) & 3;
    gA[c] = w1bf + (size_t)(co0 + row) * KDIM + slot * 8;
  }
  // B: 4 KB = 4 calls; wave w does call w.
  const short* gB;
  {
    int Y = w * 1024 + l * 16;
    int X = invswz(Y);
    int row = X >> 6, slot = (X >> 4) & 3;
    gB = BmatT + ((size_t)b * TPAD + t0 + row) * KDIM + slot * 8;
  }
  short* ldsA0 = &A_lds[(w * 2 + 0) * 512];
  short* ldsA1 = &A_lds[(w * 2 + 1) * 512];
  short* ldsB  = &B_lds[w * 512];

  const int kslot = l >> 4;
  int abyte[2];
  #pragma unroll
  for (int i = 0; i < 2; ++i) {
    int arow = w * 32 + i * 16 + (l & 15);
    abyte[i] = (arow * 64 + kslot * 16) ^ ((arow & 7) << 4);
  }
  int bbyte[4];
  #pragma unroll
  for (int g = 0; g < 4; ++g) {
    int brow = g * 16 + (l & 15);
    bbyte[g] = (brow * 64 + kslot * 16) ^ ((brow & 7) << 4);
  }

  f32x4 acc[2][4];
  #pragma unroll
  for (int i = 0; i < 2; ++i)
    #pragma unroll
    for (int g = 0; g < 4; ++g) acc[i][g] = (f32x4){0.f, 0.f, 0.f, 0.f};

  for (int kt = 0; kt < KDIM / 32; ++kt) {   // 48 iterations
    __syncthreads();                         // prior reads done
    gload_lds16(gA[0] + kt * 32, ldsA0);
    gload_lds16(gA[1] + kt * 32, ldsA1);
    gload_lds16(gB + kt * 32, ldsB);
    __syncthreads();                         // vmcnt drained -> LDS ready
    short8 a0 = *(const short8*)((const char*)A_lds + abyte[0]);
    short8 a1 = *(const short8*)((const char*)A_lds + abyte[1]);
    #pragma unroll
    for (int g = 0; g < 4; ++g) {
      short8 bb = *(const short8*)((const char*)B_lds + bbyte[g]);
      acc[0][g] = __builtin_amdgcn_mfma_f32_16x16x32_bf16(a0, bb, acc[0][g], 0, 0, 0);
      acc[1][g] = __builtin_amdgcn_mfma_f32_16x16x32_bf16(a1, bb, acc[1][g], 0, 0, 0);
    }
  }

  #pragma unroll
  for (int g = 0; g < 4; ++g) {
    int t = t0 + g * 16 + (l & 15);
    if (t < TEN) {
      #pragma unroll
      for (int i = 0; i < 2; ++i) {
        #pragma unroll
        for (int r = 0; r < 4; ++r) {
          int co = co0 + w * 32 + i * 16 + kslot * 4 + r;
          float v = acc[i][g][r] + b1[co];
          k1t[((size_t)b * TPAD + t) * C1 + co] = f2bf(v > 0.f ? v : 0.f);
        }
      }
    }
  }
}

// ---------------------------------------------------------------------------
// Generic small GEMM + prefetch (verbatim R17).
// MODE 1: bf16 [b][t][co]; MODE 2: f32 [b][co][t]
// ---------------------------------------------------------------------------
template <int MODE, bool RELU>
__global__ __launch_bounds__(256) void qgemm_kernel(
    const short* __restrict__ A, const short* __restrict__ B,
    const float* __restrict__ bias, void* __restrict__ outv,
    int M, int Kpad, int kiters, int Nvalid, int outCols,
    size_t bBatchStride, size_t outBatchStride, int outLD) {
  __shared__ short A_lds[2048];
  __shared__ short B_lds[2048];
  const int co0 = blockIdx.x * 64;
  const int t0  = blockIdx.y * 64;
  const int b   = blockIdx.z;
  const int tid = threadIdx.x;
  const int l = tid & 63, w = tid >> 6;
  const int srow = tid >> 2, sslot = tid & 3;

  const short* gA = A + (size_t)(co0 + srow) * Kpad + sslot * 8;
  const short* gB = B + (size_t)b * bBatchStride + (size_t)(t0 + srow) * Kpad + sslot * 8;
  const int wbyte = (srow * 64 + sslot * 16) ^ ((srow & 7) << 4);

  const int kslot = l >> 4;
  const int arow = w * 16 + (l & 15);
  const int abyte = (arow * 64 + kslot * 16) ^ ((arow & 7) << 4);
  int bbyte[4];
  #pragma unroll
  for (int g = 0; g < 4; ++g) {
    int brow = g * 16 + (l & 15);
    bbyte[g] = (brow * 64 + kslot * 16) ^ ((brow & 7) << 4);
  }

  f32x4 acc[4];
  #pragma unroll
  for (int g = 0; g < 4; ++g) acc[g] = (f32x4){0.f, 0.f, 0.f, 0.f};

  uint4 av = *(const uint4*)gA;
  uint4 bv = *(const uint4*)gB;
  for (int kt = 0; kt < kiters; ++kt) {
    __syncthreads();
    *(uint4*)((char*)A_lds + wbyte) = av;
    *(uint4*)((char*)B_lds + wbyte) = bv;
    __syncthreads();
    uint4 an = av, bn = bv;
    if (kt + 1 < kiters) {
      an = *(const uint4*)(gA + (kt + 1) * 32);
      bn = *(const uint4*)(gB + (kt + 1) * 32);
    }
    short8 a = *(const short8*)((const char*)A_lds + abyte);
    #pragma unroll
    for (int g = 0; g < 4; ++g) {
      short8 bb = *(const short8*)((const char*)B_lds + bbyte[g]);
      acc[g] = __builtin_amdgcn_mfma_f32_16x16x32_bf16(a, bb, acc[g], 0, 0, 0);
    }
    av = an; bv = bn;
  }

  #pragma unroll
  for (int g = 0; g < 4; ++g) {
    int t = t0 + g * 16 + (l & 15);
    if (t >= Nvalid) continue;
    #pragma unroll
    for (int r = 0; r < 4; ++r) {
      int co = co0 + w * 16 + kslot * 4 + r;
      if (MODE == 1) {
        if (co < outCols) {
          float v = 0.f;
          if (co < M) {
            v = acc[g][r] + bias[co];
            if (RELU) v = v > 0.f ? v : 0.f;
          }
          ((short*)outv)[(size_t)b * outBatchStride + (size_t)t * outLD + co] = f2bf(v);
        }
      } else {
        if (co < M) {
          float v = acc[g][r] + bias[co];
          if (RELU) v = v > 0.f ? v : 0.f;
          ((float*)outv)[(size_t)b * outBatchStride + (size_t)co * outLD + t] = v;
        }
      }
    }
  }
}

// ---------------------------------------------------------------------------
// Attn prep (verbatim R17)
// ---------------------------------------------------------------------------
__global__ __launch_bounds__(256) void prep_attn_q_kernel(
    const float* __restrict__ q3, short* __restrict__ qA,
    float* __restrict__ q2) {
  __shared__ float sm[80][64];
  const int b = blockIdx.y;
  const int t0 = blockIdx.x * 64;
  const int tid = threadIdx.x;
  for (int idx = tid; idx < 80 * 64; idx += 256) {
    int a = idx >> 6, j = idx & 63;
    int t = t0 + j;
    sm[a][j] = (t < TDE) ? q3[((size_t)b * CA + a) * TDE + t] : 0.f;
  }
  __syncthreads();
  if (tid < 64) {
    float ss = 0.f;
    #pragma unroll 8
    for (int a = 0; a < 80; ++a) { float v = sm[a][tid]; ss += v * v; }
    q2[(size_t)b * TQP + t0 + tid] = ss;
  }
  for (int idx = tid; idx < 64 * 96; idx += 256) {
    int j = idx / 96, k = idx - j * 96;
    float v = (k < 80) ? sm[k][j] : 0.f;
    qA[((size_t)b * TQP + t0 + j) * 96 + k] = f2bf(v);
  }
}

__global__ __launch_bounds__(256) void prep_attn_k_kernel(
    const float* __restrict__ kfeat, short* __restrict__ kB,
    float* __restrict__ k2) {
  __shared__ float sm[80][64];
  const int b = blockIdx.y;
  const int s0 = blockIdx.x * 64;
  const int tid = threadIdx.x;
  for (int idx = tid; idx < 80 * 64; idx += 256) {
    int a = idx >> 6, j = idx & 63;
    int s = s0 + j;
    sm[a][j] = (s < TEN) ? kfeat[((size_t)b * CA + a) * TEN + s] : 0.f;
  }
  __syncthreads();
  if (tid < 64) {
    float ss = 0.f;
    #pragma unroll 8
    for (int a = 0; a < 80; ++a) { float v = sm[a][tid]; ss += v * v; }
    k2[(size_t)b * TPAD + s0 + tid] = ss;
  }
  for (int idx = tid; idx < 64 * 96; idx += 256) {
    int j = idx / 96, k = idx - j * 96;
    float v = (k < 80) ? sm[k][j] : 0.f;
    kB[((size_t)b * TPAD + s0 + j) * 96 + k] = f2bf(v);
  }
}

// ---------------------------------------------------------------------------
// FUSED attention (verbatim R17)
// ---------------------------------------------------------------------------
__global__ __launch_bounds__(256) void attn_fused_kernel(
    const short* __restrict__ qA, const short* __restrict__ kB,
    const float* __restrict__ q2, const float* __restrict__ k2,
    const int* __restrict__ mask, float* __restrict__ out_attn,
    float* __restrict__ out_logp) {
  __shared__ short A_lds[3][2048];
  __shared__ short B_lds[3][2560];
  __shared__ float k2LDS[400];
  __shared__ int mLDS[400];
  const int t0 = blockIdx.x * 64;
  const int b  = blockIdx.y;
  const int tid = threadIdx.x;
  const int l = tid & 63, w = tid >> 6;

  {
    const int arow_s = tid >> 2, aslot = tid & 3;
    const short* gA = qA + ((size_t)b * TQP + t0 + arow_s) * 96 + aslot * 8;
    #pragma unroll
    for (int p = 0; p < 3; ++p) {
      uint4 v = *(const uint4*)(gA + p * 32);
      *(uint4*)((char*)&A_lds[p][0] +
                ((arow_s * 64 + aslot * 16) ^ ((arow_s & 7) << 4))) = v;
    }
  }
  for (int idx = tid; idx < 400; idx += 256) {
    k2LDS[idx] = k2[(size_t)b * TPAD + idx];
    mLDS[idx] = mask[(size_t)b * TEN + idx];
  }

  const int kslot = l >> 4;
  const int arow = w * 16 + (l & 15);
  const int abyte = (arow * 64 + kslot * 16) ^ ((arow & 7) << 4);

  f32x4 acc[25];
  #pragma unroll
  for (int i = 0; i < 25; ++i) acc[i] = (f32x4){0.f, 0.f, 0.f, 0.f};

  __syncthreads();
  #pragma unroll
  for (int st = 0; st < 5; ++st) {
    for (int idx = tid; idx < 960; idx += 256) {
      int row = idx / 12, c = idx - row * 12;
      int panel = c >> 2, ps = c & 3;
      uint4 v = *(const uint4*)(kB + ((size_t)b * TPAD + st * 80 + row) * 96 + c * 8);
      *(uint4*)((char*)&B_lds[panel][0] +
                ((row * 64 + ps * 16) ^ ((row & 7) << 4))) = v;
    }
    __syncthreads();
    #pragma unroll
    for (int kt = 0; kt < 3; ++kt) {
      short8 a = *(const short8*)((const char*)&A_lds[kt][0] + abyte);
      #pragma unroll
      for (int f = 0; f < 5; ++f) {
        int brow = f * 16 + (l & 15);
        short8 bb = *(const short8*)((const char*)&B_lds[kt][0] +
                                     ((brow * 64 + kslot * 16) ^ ((brow & 7) << 4)));
        acc[st * 5 + f] =
            __builtin_amdgcn_mfma_f32_16x16x32_bf16(a, bb, acc[st * 5 + f], 0, 0, 0);
      }
    }
    __syncthreads();
  }

  int trow[4]; float q2v[4];
  #pragma unroll
  for (int r = 0; r < 4; ++r) {
    trow[r] = t0 + w * 16 + kslot * 4 + r;
    q2v[r] = q2[(size_t)b * TQP + trow[r]];
  }
  #pragma unroll
  for (int sf = 0; sf < 25; ++sf) {
    int s = sf * 16 + (l & 15);
    float k2v = k2LDS[s];
    bool mk = mLDS[s] != 0;
    #pragma unroll
    for (int r = 0; r < 4; ++r) {
      float lp = mk ? (-TEMP) * (q2v[r] + k2v - 2.f * acc[sf][r]) : -INFINITY;
      acc[sf][r] = lp;
    }
  }
  #pragma unroll
  for (int r = 0; r < 4; ++r) {
    if (trow[r] < TDE) {
      float* dst = out_logp + ((size_t)(b * TDE + trow[r])) * TEN + (l & 15);
      #pragma unroll
      for (int sf = 0; sf < 25; ++sf) dst[sf * 16] = acc[sf][r];
    }
  }
  float m[4];
  #pragma unroll
  for (int r = 0; r < 4; ++r) m[r] = -INFINITY;
  #pragma unroll
  for (int sf = 0; sf < 25; ++sf)
    #pragma unroll
    for (int r = 0; r < 4; ++r) m[r] = fmaxf(m[r], acc[sf][r]);
  #pragma unroll
  for (int o = 1; o < 16; o <<= 1)
    #pragma unroll
    for (int r = 0; r < 4; ++r) m[r] = fmaxf(m[r], __shfl_xor(m[r], o, 64));
  float sum[4] = {0.f, 0.f, 0.f, 0.f};
  #pragma unroll
  for (int sf = 0; sf < 25; ++sf)
    #pragma unroll
    for (int r = 0; r < 4; ++r) {
      float v = acc[sf][r];
      float e = (v != -INFINITY) ? __expf(v - m[r]) : 0.f;
      acc[sf][r] = e;
      sum[r] += e;
    }
  #pragma unroll
  for (int o = 1; o < 16; o <<= 1)
    #pragma unroll
    for (int r = 0; r < 4; ++r) sum[r] += __shfl_xor(sum[r], o, 64);
  float inv[4];
  #pragma unroll
  for (int r = 0; r < 4; ++r) inv[r] = 1.0f / sum[r];
  #pragma unroll
  for (int r = 0; r < 4; ++r) {
    if (trow[r] < TDE) {
      float* dst = out_attn + ((size_t)(b * TDE + trow[r])) * TEN + (l & 15);
      #pragma unroll
      for (int sf = 0; sf < 25; ++sf) dst[sf * 16] = acc[sf][r] * inv[r];
    }
  }
}

extern "C" void kernel_launch(void* const* d_in, const int* in_sizes, int n_in,
                              void* d_out, int out_size, void* d_ws, size_t ws_size,
                              hipStream_t stream) {
  const float* queries = (const float*)d_in[0];
  const float* keys    = (const float*)d_in[1];
  const int*   mask    = (const int*)d_in[2];
  const float* kw1 = (const float*)d_in[3];
  const float* kb1 = (const float*)d_in[4];
  const float* kw2 = (const float*)d_in[5];
  const float* kb2 = (const float*)d_in[6];
  const float* qw1 = (const float*)d_in[7];
  const float* qb1 = (const float*)d_in[8];
  const float* qw2 = (const float*)d_in[9];
  const float* qb2 = (const float*)d_in[10];
  const float* qw3 = (const float*)d_in[11];
  const float* qb3 = (const float*)d_in[12];
  float* out = (float*)d_out;

  char* ws = (char*)d_ws;
  short* BmatT = (short*)ws;
  short* w1bf  = (short*)(ws + 44040192);
  short* k1t   = (short*)(ws + 47185920);
  short* w2bf  = (short*)(ws + 76546048);
  short* w1q   = (short*)(ws + 76808192);
  short* w2q   = (short*)(ws + 76906496);
  short* w3q   = (short*)(ws + 76947456);
  short* Bq    = (short*)ws;
  short* q1bf  = (short*)(ws + 33554432);
  short* q2bf  = (short*)(ws + 54525952);
  float* q3    = (float*)ws;
  short* qA    = (short*)(ws + 20480000);
  float* q2n   = (float*)(ws + 33062912);
  short* kB    = (short*)(ws + 47185920);
  float* k2n   = (float*)(ws + 49938432);
  float* kfeat = (float*)(ws + 81920000);

  const long long HALF = 25600000LL;
  float* out_attn = out;
  float* out_logp = out + HALF;

  // --- key path (all MFMA) ---
  cvt_w1_kernel<<<dim3((C1 * KDIM + 255) / 256), dim3(256), 0, stream>>>(kw1, w1bf);
  im2col_kernel<<<dim3(TEN, NB), dim3(256), 0, stream>>>(keys, BmatT);
  kconv1_mfma_kernel<<<dim3(8, 7, NB), dim3(256), 0, stream>>>(w1bf, BmatT, kb1, k1t);
  cvt_pad_kernel<<<dim3((128 * 1024 + 255) / 256), dim3(256), 0, stream>>>(
      kw2, w2bf, CA, C1, 128, C1);
  qgemm_kernel<2, false><<<dim3(2, 7, NB), dim3(256), 0, stream>>>(
      w2bf, k1t, kb2, kfeat, CA, C1, 32, TEN, CA,
      (size_t)TPAD * C1, (size_t)CA * TEN, TEN);

  // --- query path (MFMA chain) ---
  cvt_pad_kernel<<<dim3((192 * 256 + 255) / 256), dim3(256), 0, stream>>>(
      qw1, w1q, CQ2, 240, 192, 256);
  cvt_pad_kernel<<<dim3((128 * 160 + 255) / 256), dim3(256), 0, stream>>>(
      qw2, w2q, CA, CQ2, 128, 160);
  cvt_pad_kernel<<<dim3((128 * 96 + 255) / 256), dim3(256), 0, stream>>>(
      qw3, w3q, CA, CQ, 128, 96);
  im2col_q_kernel<<<dim3(TQP, NB), dim3(256), 0, stream>>>(queries, Bq);
  qgemm_kernel<1, true><<<dim3(3, TQP / 64, NB), dim3(256), 0, stream>>>(
      w1q, Bq, qb1, q1bf, CQ2, 256, 8, TDE, 160,
      (size_t)TQP * 256, (size_t)TQP * 160, 160);
  qgemm_kernel<1, true><<<dim3(2, TQP / 64, NB), dim3(256), 0, stream>>>(
      w2q, q1bf, qb2, q2bf, CA, 160, 5, TDE, 96,
      (size_t)TQP * 160, (size_t)TQP * 96, 96);
  qgemm_kernel<2, false><<<dim3(2, TQP / 64, NB), dim3(256), 0, stream>>>(
      w3q, q2bf, qb3, q3, CA, 96, 3, TDE, 80,
      (size_t)TQP * 96, (size_t)CA * TDE, TDE);

  // --- attention: prep -> fused QK^T + softmax ---
  prep_attn_q_kernel<<<dim3(TQP / 64, NB), dim3(256), 0, stream>>>(q3, qA, q2n);
  prep_attn_k_kernel<<<dim3(TPAD / 64, NB), dim3(256), 0, stream>>>(kfeat, kB, k2n);
  attn_fused_kernel<<<dim3(TQP / 64, NB), dim3(256), 0, stream>>>(
      qA, kB, q2n, k2n, mask, out_attn, out_logp);
}

// Round 19
// 370.290 us; speedup vs baseline: 2.0131x; 1.0261x over previous
//
#include <hip/hip_runtime.h>
#include <hip/hip_bf16.h>
#include <math.h>

#define NB 32
#define CK 512
#define C1 1024
#define CA 80
#define CQ 80
#define CQ2 160
#define TEN 400
#define TDE 2000
#define KDIM 1536
#define TPAD 448
#define TQP 2048

static constexpr float TEMP = 0.0005f;

typedef __attribute__((ext_vector_type(8))) short short8;
typedef __attribute__((ext_vector_type(4))) float f32x4;

__device__ inline short f2bf(float v) {
  __hip_bfloat16 h = __float2bfloat16(v);
  return *(short*)&h;
}

__device__ inline void gload_lds16(const void* g, void* l) {
  __builtin_amdgcn_global_load_lds(
      (const __attribute__((address_space(1))) unsigned int*)g,
      (__attribute__((address_space(3))) unsigned int*)l, 16, 0, 0);
}

// ---------------------------------------------------------------------------
// Prepass: w1 f32[1024][1536] -> bf16
// ---------------------------------------------------------------------------
__global__ __launch_bounds__(256) void cvt_w1_kernel(
    const float* __restrict__ w1, short* __restrict__ w1bf) {
  int i = blockIdx.x * 256 + threadIdx.x;
  if (i < C1 * KDIM) w1bf[i] = f2bf(w1[i]);
}

__global__ __launch_bounds__(256) void cvt_pad_kernel(
    const float* __restrict__ src, short* __restrict__ dst,
    int M, int K, int Mp, int Kp) {
  int i = blockIdx.x * 256 + threadIdx.x;
  if (i >= Mp * Kp) return;
  int r = i / Kp, c = i - r * Kp;
  float v = (r < M && c < K) ? src[(size_t)r * K + c] : 0.f;
  dst[i] = f2bf(v);
}

__global__ __launch_bounds__(256) void im2col_kernel(
    const float* __restrict__ keys, short* __restrict__ BmatT) {
  const int t = blockIdx.x;
  const int b = blockIdx.y;
  const int tid = threadIdx.x;
  short* dst = BmatT + ((size_t)b * TPAD + t) * KDIM;
  #pragma unroll
  for (int i = 0; i < 6; ++i) {
    int k = tid + i * 256;
    int ci = k / 3;
    int dk = k - ci * 3;
    int ts = t + dk - 1;
    float v = (ts >= 0 && ts < TEN) ? keys[((size_t)b * CK + ci) * TEN + ts] : 0.f;
    dst[k] = f2bf(v);
  }
}

__global__ __launch_bounds__(256) void im2col_q_kernel(
    const float* __restrict__ queries, short* __restrict__ Bq) {
  const int t = blockIdx.x;
  const int b = blockIdx.y;
  const int k = threadIdx.x;
  float v = 0.f;
  if (t < TDE && k < 240) {
    int ci = k / 3, dk = k - ci * 3, ts = t + dk - 1;
    v = (ts >= 0 && ts < TDE) ? queries[((size_t)b * CQ + ci) * TDE + ts] : 0.f;
  }
  Bq[((size_t)b * TQP + t) * 256 + k] = f2bf(v);
}

// ---------------------------------------------------------------------------
// Key conv1 via MFMA v4: 128co x 128t tile, global_load_lds(16B) staging,
// L2-locality block remap (B-panel peers spaced 128 apart -> same XCD).
// B-row staging clamped to TPAD-1 (garbage columns dropped by t<TEN guard).
// -> k1t[b][t][co] bf16
// ---------------------------------------------------------------------------
__global__ __launch_bounds__(256) void kconv1_mfma_kernel(
    const short* __restrict__ w1bf, const short* __restrict__ BmatT,
    const float* __restrict__ b1, short* __restrict__ k1t) {
  __shared__ short A_lds[4096];   // 128 rows x 32 k (8 KB)
  __shared__ short B_lds[4096];   // 128 rows x 32 k (8 KB)
  const int flat = blockIdx.x;    // 0..1023
  const int cox = flat >> 7;      // 0..7
  const int rem = flat & 127;
  const int b   = rem >> 2;       // 0..31
  const int ty  = rem & 3;        // 0..3
  const int co0 = cox * 128;
  const int t0  = ty * 128;
  const int tid = threadIdx.x;
  const int l = tid & 63, w = tid >> 6;

  // inverse of Y = X ^ (((X>>6)&7)<<4)  (proven R18)
  auto invswz = [](int Y) {
    int X = Y;
    X ^= ((Y >> 8) & 1) << 6;
    X ^= ((Y >> 7) & 1) << 5;
    X ^= (((Y >> 6) ^ (Y >> 8)) & 1) << 4;
    return X;
  };

  // 16 staging calls of 1024B: calls 0..7 = A, 8..15 = B. Wave w: calls w*4+j.
  const short* gsrc[4];
  short* ldst[4];
  #pragma unroll
  for (int j = 0; j < 4; ++j) {
    int c = w * 4 + j;
    int Y = (c & 7) * 1024 + l * 16;
    int X = invswz(Y);
    int row = X >> 6, slot = (X >> 4) & 3;
    if (c < 8) {
      gsrc[j] = w1bf + (size_t)(co0 + row) * KDIM + slot * 8;
      ldst[j] = &A_lds[(c & 7) * 512];
    } else {
      int gr = t0 + row;
      if (gr > TPAD - 1) gr = TPAD - 1;   // clamp: in-bounds garbage, dropped
      gsrc[j] = BmatT + ((size_t)b * TPAD + gr) * KDIM + slot * 8;
      ldst[j] = &B_lds[(c & 7) * 512];
    }
  }

  const int kslot = l >> 4;
  int abyte[2];
  #pragma unroll
  for (int i = 0; i < 2; ++i) {
    int arow = w * 32 + i * 16 + (l & 15);
    abyte[i] = (arow * 64 + kslot * 16) ^ ((arow & 7) << 4);
  }
  int bbyte[8];
  #pragma unroll
  for (int g = 0; g < 8; ++g) {
    int brow = g * 16 + (l & 15);
    bbyte[g] = (brow * 64 + kslot * 16) ^ ((brow & 7) << 4);
  }

  f32x4 acc[2][8];
  #pragma unroll
  for (int i = 0; i < 2; ++i)
    #pragma unroll
    for (int g = 0; g < 8; ++g) acc[i][g] = (f32x4){0.f, 0.f, 0.f, 0.f};

  for (int kt = 0; kt < KDIM / 32; ++kt) {   // 48 iterations
    __syncthreads();                         // prior reads done
    #pragma unroll
    for (int j = 0; j < 4; ++j) gload_lds16(gsrc[j] + kt * 32, ldst[j]);
    __syncthreads();                         // vmcnt drained -> LDS ready
    short8 a0 = *(const short8*)((const char*)A_lds + abyte[0]);
    short8 a1 = *(const short8*)((const char*)A_lds + abyte[1]);
    #pragma unroll
    for (int g = 0; g < 8; ++g) {
      short8 bb = *(const short8*)((const char*)B_lds + bbyte[g]);
      acc[0][g] = __builtin_amdgcn_mfma_f32_16x16x32_bf16(a0, bb, acc[0][g], 0, 0, 0);
      acc[1][g] = __builtin_amdgcn_mfma_f32_16x16x32_bf16(a1, bb, acc[1][g], 0, 0, 0);
    }
  }

  #pragma unroll
  for (int g = 0; g < 8; ++g) {
    int t = t0 + g * 16 + (l & 15);
    if (t < TEN) {
      #pragma unroll
      for (int i = 0; i < 2; ++i) {
        #pragma unroll
        for (int r = 0; r < 4; ++r) {
          int co = co0 + w * 32 + i * 16 + kslot * 4 + r;
          float v = acc[i][g][r] + b1[co];
          k1t[((size_t)b * TPAD + t) * C1 + co] = f2bf(v > 0.f ? v : 0.f);
        }
      }
    }
  }
}

// ---------------------------------------------------------------------------
// Generic small GEMM + prefetch (verbatim R17/R18).
// MODE 1: bf16 [b][t][co]; MODE 2: f32 [b][co][t]
// ---------------------------------------------------------------------------
template <int MODE, bool RELU>
__global__ __launch_bounds__(256) void qgemm_kernel(
    const short* __restrict__ A, const short* __restrict__ B,
    const float* __restrict__ bias, void* __restrict__ outv,
    int M, int Kpad, int kiters, int Nvalid, int outCols,
    size_t bBatchStride, size_t outBatchStride, int outLD) {
  __shared__ short A_lds[2048];
  __shared__ short B_lds[2048];
  const int co0 = blockIdx.x * 64;
  const int t0  = blockIdx.y * 64;
  const int b   = blockIdx.z;
  const int tid = threadIdx.x;
  const int l = tid & 63, w = tid >> 6;
  const int srow = tid >> 2, sslot = tid & 3;

  const short* gA = A + (size_t)(co0 + srow) * Kpad + sslot * 8;
  const short* gB = B + (size_t)b * bBatchStride + (size_t)(t0 + srow) * Kpad + sslot * 8;
  const int wbyte = (srow * 64 + sslot * 16) ^ ((srow & 7) << 4);

  const int kslot = l >> 4;
  const int arow = w * 16 + (l & 15);
  const int abyte = (arow * 64 + kslot * 16) ^ ((arow & 7) << 4);
  int bbyte[4];
  #pragma unroll
  for (int g = 0; g < 4; ++g) {
    int brow = g * 16 + (l & 15);
    bbyte[g] = (brow * 64 + kslot * 16) ^ ((brow & 7) << 4);
  }

  f32x4 acc[4];
  #pragma unroll
  for (int g = 0; g < 4; ++g) acc[g] = (f32x4){0.f, 0.f, 0.f, 0.f};

  uint4 av = *(const uint4*)gA;
  uint4 bv = *(const uint4*)gB;
  for (int kt = 0; kt < kiters; ++kt) {
    __syncthreads();
    *(uint4*)((char*)A_lds + wbyte) = av;
    *(uint4*)((char*)B_lds + wbyte) = bv;
    __syncthreads();
    uint4 an = av, bn = bv;
    if (kt + 1 < kiters) {
      an = *(const uint4*)(gA + (kt + 1) * 32);
      bn = *(const uint4*)(gB + (kt + 1) * 32);
    }
    short8 a = *(const short8*)((const char*)A_lds + abyte);
    #pragma unroll
    for (int g = 0; g < 4; ++g) {
      short8 bb = *(const short8*)((const char*)B_lds + bbyte[g]);
      acc[g] = __builtin_amdgcn_mfma_f32_16x16x32_bf16(a, bb, acc[g], 0, 0, 0);
    }
    av = an; bv = bn;
  }

  #pragma unroll
  for (int g = 0; g < 4; ++g) {
    int t = t0 + g * 16 + (l & 15);
    if (t >= Nvalid) continue;
    #pragma unroll
    for (int r = 0; r < 4; ++r) {
      int co = co0 + w * 16 + kslot * 4 + r;
      if (MODE == 1) {
        if (co < outCols) {
          float v = 0.f;
          if (co < M) {
            v = acc[g][r] + bias[co];
            if (RELU) v = v > 0.f ? v : 0.f;
          }
          ((short*)outv)[(size_t)b * outBatchStride + (size_t)t * outLD + co] = f2bf(v);
        }
      } else {
        if (co < M) {
          float v = acc[g][r] + bias[co];
          if (RELU) v = v > 0.f ? v : 0.f;
          ((float*)outv)[(size_t)b * outBatchStride + (size_t)co * outLD + t] = v;
        }
      }
    }
  }
}

// ---------------------------------------------------------------------------
// Attn prep (verbatim R17/R18)
// ---------------------------------------------------------------------------
__global__ __launch_bounds__(256) void prep_attn_q_kernel(
    const float* __restrict__ q3, short* __restrict__ qA,
    float* __restrict__ q2) {
  __shared__ float sm[80][64];
  const int b = blockIdx.y;
  const int t0 = blockIdx.x * 64;
  const int tid = threadIdx.x;
  for (int idx = tid; idx < 80 * 64; idx += 256) {
    int a = idx >> 6, j = idx & 63;
    int t = t0 + j;
    sm[a][j] = (t < TDE) ? q3[((size_t)b * CA + a) * TDE + t] : 0.f;
  }
  __syncthreads();
  if (tid < 64) {
    float ss = 0.f;
    #pragma unroll 8
    for (int a = 0; a < 80; ++a) { float v = sm[a][tid]; ss += v * v; }
    q2[(size_t)b * TQP + t0 + tid] = ss;
  }
  for (int idx = tid; idx < 64 * 96; idx += 256) {
    int j = idx / 96, k = idx - j * 96;
    float v = (k < 80) ? sm[k][j] : 0.f;
    qA[((size_t)b * TQP + t0 + j) * 96 + k] = f2bf(v);
  }
}

__global__ __launch_bounds__(256) void prep_attn_k_kernel(
    const float* __restrict__ kfeat, short* __restrict__ kB,
    float* __restrict__ k2) {
  __shared__ float sm[80][64];
  const int b = blockIdx.y;
  const int s0 = blockIdx.x * 64;
  const int tid = threadIdx.x;
  for (int idx = tid; idx < 80 * 64; idx += 256) {
    int a = idx >> 6, j = idx & 63;
    int s = s0 + j;
    sm[a][j] = (s < TEN) ? kfeat[((size_t)b * CA + a) * TEN + s] : 0.f;
  }
  __syncthreads();
  if (tid < 64) {
    float ss = 0.f;
    #pragma unroll 8
    for (int a = 0; a < 80; ++a) { float v = sm[a][tid]; ss += v * v; }
    k2[(size_t)b * TPAD + s0 + tid] = ss;
  }
  for (int idx = tid; idx < 64 * 96; idx += 256) {
    int j = idx / 96, k = idx - j * 96;
    float v = (k < 80) ? sm[k][j] : 0.f;
    kB[((size_t)b * TPAD + s0 + j) * 96 + k] = f2bf(v);
  }
}

// ---------------------------------------------------------------------------
// FUSED attention (verbatim R17/R18)
// ---------------------------------------------------------------------------
__global__ __launch_bounds__(256) void attn_fused_kernel(
    const short* __restrict__ qA, const short* __restrict__ kB,
    const float* __restrict__ q2, const float* __restrict__ k2,
    const int* __restrict__ mask, float* __restrict__ out_attn,
    float* __restrict__ out_logp) {
  __shared__ short A_lds[3][2048];
  __shared__ short B_lds[3][2560];
  __shared__ float k2LDS[400];
  __shared__ int mLDS[400];
  const int t0 = blockIdx.x * 64;
  const int b  = blockIdx.y;
  const int tid = threadIdx.x;
  const int l = tid & 63, w = tid >> 6;

  {
    const int arow_s = tid >> 2, aslot = tid & 3;
    const short* gA = qA + ((size_t)b * TQP + t0 + arow_s) * 96 + aslot * 8;
    #pragma unroll
    for (int p = 0; p < 3; ++p) {
      uint4 v = *(const uint4*)(gA + p * 32);
      *(uint4*)((char*)&A_lds[p][0] +
                ((arow_s * 64 + aslot * 16) ^ ((arow_s & 7) << 4))) = v;
    }
  }
  for (int idx = tid; idx < 400; idx += 256) {
    k2LDS[idx] = k2[(size_t)b * TPAD + idx];
    mLDS[idx] = mask[(size_t)b * TEN + idx];
  }

  const int kslot = l >> 4;
  const int arow = w * 16 + (l & 15);
  const int abyte = (arow * 64 + kslot * 16) ^ ((arow & 7) << 4);

  f32x4 acc[25];
  #pragma unroll
  for (int i = 0; i < 25; ++i) acc[i] = (f32x4){0.f, 0.f, 0.f, 0.f};

  __syncthreads();
  #pragma unroll
  for (int st = 0; st < 5; ++st) {
    for (int idx = tid; idx < 960; idx += 256) {
      int row = idx / 12, c = idx - row * 12;
      int panel = c >> 2, ps = c & 3;
      uint4 v = *(const uint4*)(kB + ((size_t)b * TPAD + st * 80 + row) * 96 + c * 8);
      *(uint4*)((char*)&B_lds[panel][0] +
                ((row * 64 + ps * 16) ^ ((row & 7) << 4))) = v;
    }
    __syncthreads();
    #pragma unroll
    for (int kt = 0; kt < 3; ++kt) {
      short8 a = *(const short8*)((const char*)&A_lds[kt][0] + abyte);
      #pragma unroll
      for (int f = 0; f < 5; ++f) {
        int brow = f * 16 + (l & 15);
        short8 bb = *(const short8*)((const char*)&B_lds[kt][0] +
                                     ((brow * 64 + kslot * 16) ^ ((brow & 7) << 4)));
        acc[st * 5 + f] =
            __builtin_amdgcn_mfma_f32_16x16x32_bf16(a, bb, acc[st * 5 + f], 0, 0, 0);
      }
    }
    __syncthreads();
  }

  int trow[4]; float q2v[4];
  #pragma unroll
  for (int r = 0; r < 4; ++r) {
    trow[r] = t0 + w * 16 + kslot * 4 + r;
    q2v[r] = q2[(size_t)b * TQP + trow[r]];
  }
  #pragma unroll
  for (int sf = 0; sf < 25; ++sf) {
    int s = sf * 16 + (l & 15);
    float k2v = k2LDS[s];
    bool mk = mLDS[s] != 0;
    #pragma unroll
    for (int r = 0; r < 4; ++r) {
      float lp = mk ? (-TEMP) * (q2v[r] + k2v - 2.f * acc[sf][r]) : -INFINITY;
      acc[sf][r] = lp;
    }
  }
  #pragma unroll
  for (int r = 0; r < 4; ++r) {
    if (trow[r] < TDE) {
      float* dst = out_logp + ((size_t)(b * TDE + trow[r])) * TEN + (l & 15);
      #pragma unroll
      for (int sf = 0; sf < 25; ++sf) dst[sf * 16] = acc[sf][r];
    }
  }
  float m[4];
  #pragma unroll
  for (int r = 0; r < 4; ++r) m[r] = -INFINITY;
  #pragma unroll
  for (int sf = 0; sf < 25; ++sf)
    #pragma unroll
    for (int r = 0; r < 4; ++r) m[r] = fmaxf(m[r], acc[sf][r]);
  #pragma unroll
  for (int o = 1; o < 16; o <<= 1)
    #pragma unroll
    for (int r = 0; r < 4; ++r) m[r] = fmaxf(m[r], __shfl_xor(m[r], o, 64));
  float sum[4] = {0.f, 0.f, 0.f, 0.f};
  #pragma unroll
  for (int sf = 0; sf < 25; ++sf)
    #pragma unroll
    for (int r = 0; r < 4; ++r) {
      float v = acc[sf][r];
      float e = (v != -INFINITY) ? __expf(v - m[r]) : 0.f;
      acc[sf][r] = e;
      sum[r] += e;
    }
  #pragma unroll
  for (int o = 1; o < 16; o <<= 1)
    #pragma unroll
    for (int r = 0; r < 4; ++r) sum[r] += __shfl_xor(sum[r], o, 64);
  float inv[4];
  #pragma unroll
  for (int r = 0; r < 4; ++r) inv[r] = 1.0f / sum[r];
  #pragma unroll
  for (int r = 0; r < 4; ++r) {
    if (trow[r] < TDE) {
      float* dst = out_attn + ((size_t)(b * TDE + trow[r])) * TEN + (l & 15);
      #pragma unroll
      for (int sf = 0; sf < 25; ++sf) dst[sf * 16] = acc[sf][r] * inv[r];
    }
  }
}

extern "C" void kernel_launch(void* const* d_in, const int* in_sizes, int n_in,
                              void* d_out, int out_size, void* d_ws, size_t ws_size,
                              hipStream_t stream) {
  const float* queries = (const float*)d_in[0];
  const float* keys    = (const float*)d_in[1];
  const int*   mask    = (const int*)d_in[2];
  const float* kw1 = (const float*)d_in[3];
  const float* kb1 = (const float*)d_in[4];
  const float* kw2 = (const float*)d_in[5];
  const float* kb2 = (const float*)d_in[6];
  const float* qw1 = (const float*)d_in[7];
  const float* qb1 = (const float*)d_in[8];
  const float* qw2 = (const float*)d_in[9];
  const float* qb2 = (const float*)d_in[10];
  const float* qw3 = (const float*)d_in[11];
  const float* qb3 = (const float*)d_in[12];
  float* out = (float*)d_out;

  char* ws = (char*)d_ws;
  short* BmatT = (short*)ws;
  short* w1bf  = (short*)(ws + 44040192);
  short* k1t   = (short*)(ws + 47185920);
  short* w2bf  = (short*)(ws + 76546048);
  short* w1q   = (short*)(ws + 76808192);
  short* w2q   = (short*)(ws + 76906496);
  short* w3q   = (short*)(ws + 76947456);
  short* Bq    = (short*)ws;
  short* q1bf  = (short*)(ws + 33554432);
  short* q2bf  = (short*)(ws + 54525952);
  float* q3    = (float*)ws;
  short* qA    = (short*)(ws + 20480000);
  float* q2n   = (float*)(ws + 33062912);
  short* kB    = (short*)(ws + 47185920);
  float* k2n   = (float*)(ws + 49938432);
  float* kfeat = (float*)(ws + 81920000);

  const long long HALF = 25600000LL;
  float* out_attn = out;
  float* out_logp = out + HALF;

  // --- key path (all MFMA) ---
  cvt_w1_kernel<<<dim3((C1 * KDIM + 255) / 256), dim3(256), 0, stream>>>(kw1, w1bf);
  im2col_kernel<<<dim3(TEN, NB), dim3(256), 0, stream>>>(keys, BmatT);
  kconv1_mfma_kernel<<<dim3(1024), dim3(256), 0, stream>>>(w1bf, BmatT, kb1, k1t);
  cvt_pad_kernel<<<dim3((128 * 1024 + 255) / 256), dim3(256), 0, stream>>>(
      kw2, w2bf, CA, C1, 128, C1);
  qgemm_kernel<2, false><<<dim3(2, 7, NB), dim3(256), 0, stream>>>(
      w2bf, k1t, kb2, kfeat, CA, C1, 32, TEN, CA,
      (size_t)TPAD * C1, (size_t)CA * TEN, TEN);

  // --- query path (MFMA chain) ---
  cvt_pad_kernel<<<dim3((192 * 256 + 255) / 256), dim3(256), 0, stream>>>(
      qw1, w1q, CQ2, 240, 192, 256);
  cvt_pad_kernel<<<dim3((128 * 160 + 255) / 256), dim3(256), 0, stream>>>(
      qw2, w2q, CA, CQ2, 128, 160);
  cvt_pad_kernel<<<dim3((128 * 96 + 255) / 256), dim3(256), 0, stream>>>(
      qw3, w3q, CA, CQ, 128, 96);
  im2col_q_kernel<<<dim3(TQP, NB), dim3(256), 0, stream>>>(queries, Bq);
  qgemm_kernel<1, true><<<dim3(3, TQP / 64, NB), dim3(256), 0, stream>>>(
      w1q, Bq, qb1, q1bf, CQ2, 256, 8, TDE, 160,
      (size_t)TQP * 256, (size_t)TQP * 160, 160);
  qgemm_kernel<1, true><<<dim3(2, TQP / 64, NB), dim3(256), 0, stream>>>(
      w2q, q1bf, qb2, q2bf, CA, 160, 5, TDE, 96,
      (size_t)TQP * 160, (size_t)TQP * 96, 96);
  qgemm_kernel<2, false><<<dim3(2, TQP / 64, NB), dim3(256), 0, stream>>>(
      w3q, q2bf, qb3, q3, CA, 96, 3, TDE, 80,
      (size_t)TQP * 96, (size_t)CA * TDE, TDE);

  // --- attention: prep -> fused QK^T + softmax ---
  prep_attn_q_kernel<<<dim3(TQP / 64, NB), dim3(256), 0, stream>>>(q3, qA, q2n);
  prep_attn_k_kernel<<<dim3(TPAD / 64, NB), dim3(256), 0, stream>>>(kfeat, kB, k2n);
  attn_fused_kernel<<<dim3(TQP / 64, NB), dim3(256), 0, stream>>>(
      qA, kB, q2n, k2n, mask, out_attn, out_logp);
}

// Round 20
// 343.052 us; speedup vs baseline: 2.1729x; 1.0794x over previous
//
#include <hip/hip_runtime.h>
#include <hip/hip_bf16.h>
#include <math.h>

#define NB 32
#define CK 512
#define C1 1024
#define CA 80
#define CQ 80
#define CQ2 160
#define TEN 400
#define TDE 2000
#define KDIM 1536
#define TPAD 448
#define TQP 2048

static constexpr float TEMP = 0.0005f;

typedef __attribute__((ext_vector_type(8))) short short8;
typedef __attribute__((ext_vector_type(4))) float f32x4;

__device__ inline short f2bf(float v) {
  __hip_bfloat16 h = __float2bfloat16(v);
  return *(short*)&h;
}
__device__ inline float bf2f(short s) {
  __hip_bfloat16 h = *(__hip_bfloat16*)&s;
  return __bfloat162float(h);
}

__device__ inline void gload_lds16(const void* g, void* l) {
  __builtin_amdgcn_global_load_lds(
      (const __attribute__((address_space(1))) unsigned int*)g,
      (__attribute__((address_space(3))) unsigned int*)l, 16, 0, 0);
}

// ---------------------------------------------------------------------------
// Fused weight conversion: all 5 weight tensors -> bf16 (padded) in ONE launch.
// seg0 w1bf 1024x1536 | seg1 w2bf 128x1024 | seg2 w1q 192x256 |
// seg3 w2q 128x160 | seg4 w3q 128x96.  Total 1,785,856 elems = 6976 blocks.
// ---------------------------------------------------------------------------
__global__ __launch_bounds__(256) void cvt_weights_kernel(
    const float* __restrict__ kw1, const float* __restrict__ kw2,
    const float* __restrict__ qw1, const float* __restrict__ qw2,
    const float* __restrict__ qw3, short* __restrict__ w1bf,
    short* __restrict__ w2bf, short* __restrict__ w1q,
    short* __restrict__ w2q, short* __restrict__ w3q) {
  int i = blockIdx.x * 256 + threadIdx.x;
  if (i < 1572864) {
    w1bf[i] = f2bf(kw1[i]);
    return;
  }
  i -= 1572864;
  if (i < 131072) {
    int r = i >> 10, c = i & 1023;
    w2bf[i] = f2bf(r < CA ? kw2[r * 1024 + c] : 0.f);
    return;
  }
  i -= 131072;
  if (i < 49152) {
    int r = i >> 8, c = i & 255;
    w1q[i] = f2bf((r < CQ2 && c < 240) ? qw1[r * 240 + c] : 0.f);
    return;
  }
  i -= 49152;
  if (i < 20480) {
    int r = i / 160, c = i - r * 160;
    w2q[i] = f2bf(r < CA ? qw2[r * 160 + c] : 0.f);
    return;
  }
  i -= 20480;
  if (i < 12288) {
    int r = i / 96, c = i - r * 96;
    w3q[i] = f2bf((r < CA && c < CQ) ? qw3[r * 80 + c] : 0.f);
  }
}

__global__ __launch_bounds__(256) void im2col_kernel(
    const float* __restrict__ keys, short* __restrict__ BmatT) {
  const int t = blockIdx.x;
  const int b = blockIdx.y;
  const int tid = threadIdx.x;
  short* dst = BmatT + ((size_t)b * TPAD + t) * KDIM;
  #pragma unroll
  for (int i = 0; i < 6; ++i) {
    int k = tid + i * 256;
    int ci = k / 3;
    int dk = k - ci * 3;
    int ts = t + dk - 1;
    float v = (ts >= 0 && ts < TEN) ? keys[((size_t)b * CK + ci) * TEN + ts] : 0.f;
    dst[k] = f2bf(v);
  }
}

__global__ __launch_bounds__(256) void im2col_q_kernel(
    const float* __restrict__ queries, short* __restrict__ Bq) {
  const int t = blockIdx.x;
  const int b = blockIdx.y;
  const int k = threadIdx.x;
  float v = 0.f;
  if (t < TDE && k < 240) {
    int ci = k / 3, dk = k - ci * 3, ts = t + dk - 1;
    v = (ts >= 0 && ts < TDE) ? queries[((size_t)b * CQ + ci) * TDE + ts] : 0.f;
  }
  Bq[((size_t)b * TQP + t) * 256 + k] = f2bf(v);
}

// ---------------------------------------------------------------------------
// Key conv1 via MFMA v4 (verbatim R19): 128x128 tile, gload_lds(16B),
// L2-locality remap. -> k1t[b][t][co] bf16
// ---------------------------------------------------------------------------
__global__ __launch_bounds__(256) void kconv1_mfma_kernel(
    const short* __restrict__ w1bf, const short* __restrict__ BmatT,
    const float* __restrict__ b1, short* __restrict__ k1t) {
  __shared__ short A_lds[4096];
  __shared__ short B_lds[4096];
  const int flat = blockIdx.x;
  const int cox = flat >> 7;
  const int rem = flat & 127;
  const int b   = rem >> 2;
  const int ty  = rem & 3;
  const int co0 = cox * 128;
  const int t0  = ty * 128;
  const int tid = threadIdx.x;
  const int l = tid & 63, w = tid >> 6;

  auto invswz = [](int Y) {
    int X = Y;
    X ^= ((Y >> 8) & 1) << 6;
    X ^= ((Y >> 7) & 1) << 5;
    X ^= (((Y >> 6) ^ (Y >> 8)) & 1) << 4;
    return X;
  };

  const short* gsrc[4];
  short* ldst[4];
  #pragma unroll
  for (int j = 0; j < 4; ++j) {
    int c = w * 4 + j;
    int Y = (c & 7) * 1024 + l * 16;
    int X = invswz(Y);
    int row = X >> 6, slot = (X >> 4) & 3;
    if (c < 8) {
      gsrc[j] = w1bf + (size_t)(co0 + row) * KDIM + slot * 8;
      ldst[j] = &A_lds[(c & 7) * 512];
    } else {
      int gr = t0 + row;
      if (gr > TPAD - 1) gr = TPAD - 1;
      gsrc[j] = BmatT + ((size_t)b * TPAD + gr) * KDIM + slot * 8;
      ldst[j] = &B_lds[(c & 7) * 512];
    }
  }

  const int kslot = l >> 4;
  int abyte[2];
  #pragma unroll
  for (int i = 0; i < 2; ++i) {
    int arow = w * 32 + i * 16 + (l & 15);
    abyte[i] = (arow * 64 + kslot * 16) ^ ((arow & 7) << 4);
  }
  int bbyte[8];
  #pragma unroll
  for (int g = 0; g < 8; ++g) {
    int brow = g * 16 + (l & 15);
    bbyte[g] = (brow * 64 + kslot * 16) ^ ((brow & 7) << 4);
  }

  f32x4 acc[2][8];
  #pragma unroll
  for (int i = 0; i < 2; ++i)
    #pragma unroll
    for (int g = 0; g < 8; ++g) acc[i][g] = (f32x4){0.f, 0.f, 0.f, 0.f};

  for (int kt = 0; kt < KDIM / 32; ++kt) {
    __syncthreads();
    #pragma unroll
    for (int j = 0; j < 4; ++j) gload_lds16(gsrc[j] + kt * 32, ldst[j]);
    __syncthreads();
    short8 a0 = *(const short8*)((const char*)A_lds + abyte[0]);
    short8 a1 = *(const short8*)((const char*)A_lds + abyte[1]);
    #pragma unroll
    for (int g = 0; g < 8; ++g) {
      short8 bb = *(const short8*)((const char*)B_lds + bbyte[g]);
      acc[0][g] = __builtin_amdgcn_mfma_f32_16x16x32_bf16(a0, bb, acc[0][g], 0, 0, 0);
      acc[1][g] = __builtin_amdgcn_mfma_f32_16x16x32_bf16(a1, bb, acc[1][g], 0, 0, 0);
    }
  }

  #pragma unroll
  for (int g = 0; g < 8; ++g) {
    int t = t0 + g * 16 + (l & 15);
    if (t < TEN) {
      #pragma unroll
      for (int i = 0; i < 2; ++i) {
        #pragma unroll
        for (int r = 0; r < 4; ++r) {
          int co = co0 + w * 32 + i * 16 + kslot * 4 + r;
          float v = acc[i][g][r] + b1[co];
          k1t[((size_t)b * TPAD + t) * C1 + co] = f2bf(v > 0.f ? v : 0.f);
        }
      }
    }
  }
}

// ---------------------------------------------------------------------------
// Generic small GEMM + prefetch (verbatim R17-R19 template).
// MODE 1: bf16 [b][t][co] (cols in [M,outCols) zeroed); MODE 2: f32 [b][co][t]
// ---------------------------------------------------------------------------
template <int MODE, bool RELU>
__global__ __launch_bounds__(256) void qgemm_kernel(
    const short* __restrict__ A, const short* __restrict__ B,
    const float* __restrict__ bias, void* __restrict__ outv,
    int M, int Kpad, int kiters, int Nvalid, int outCols,
    size_t bBatchStride, size_t outBatchStride, int outLD) {
  __shared__ short A_lds[2048];
  __shared__ short B_lds[2048];
  const int co0 = blockIdx.x * 64;
  const int t0  = blockIdx.y * 64;
  const int b   = blockIdx.z;
  const int tid = threadIdx.x;
  const int l = tid & 63, w = tid >> 6;
  const int srow = tid >> 2, sslot = tid & 3;

  const short* gA = A + (size_t)(co0 + srow) * Kpad + sslot * 8;
  const short* gB = B + (size_t)b * bBatchStride + (size_t)(t0 + srow) * Kpad + sslot * 8;
  const int wbyte = (srow * 64 + sslot * 16) ^ ((srow & 7) << 4);

  const int kslot = l >> 4;
  const int arow = w * 16 + (l & 15);
  const int abyte = (arow * 64 + kslot * 16) ^ ((arow & 7) << 4);
  int bbyte[4];
  #pragma unroll
  for (int g = 0; g < 4; ++g) {
    int brow = g * 16 + (l & 15);
    bbyte[g] = (brow * 64 + kslot * 16) ^ ((brow & 7) << 4);
  }

  f32x4 acc[4];
  #pragma unroll
  for (int g = 0; g < 4; ++g) acc[g] = (f32x4){0.f, 0.f, 0.f, 0.f};

  uint4 av = *(const uint4*)gA;
  uint4 bv = *(const uint4*)gB;
  for (int kt = 0; kt < kiters; ++kt) {
    __syncthreads();
    *(uint4*)((char*)A_lds + wbyte) = av;
    *(uint4*)((char*)B_lds + wbyte) = bv;
    __syncthreads();
    uint4 an = av, bn = bv;
    if (kt + 1 < kiters) {
      an = *(const uint4*)(gA + (kt + 1) * 32);
      bn = *(const uint4*)(gB + (kt + 1) * 32);
    }
    short8 a = *(const short8*)((const char*)A_lds + abyte);
    #pragma unroll
    for (int g = 0; g < 4; ++g) {
      short8 bb = *(const short8*)((const char*)B_lds + bbyte[g]);
      acc[g] = __builtin_amdgcn_mfma_f32_16x16x32_bf16(a, bb, acc[g], 0, 0, 0);
    }
    av = an; bv = bn;
  }

  #pragma unroll
  for (int g = 0; g < 4; ++g) {
    int t = t0 + g * 16 + (l & 15);
    if (t >= Nvalid) continue;
    #pragma unroll
    for (int r = 0; r < 4; ++r) {
      int co = co0 + w * 16 + kslot * 4 + r;
      if (MODE == 1) {
        if (co < outCols) {
          float v = 0.f;
          if (co < M) {
            v = acc[g][r] + bias[co];
            if (RELU) v = v > 0.f ? v : 0.f;
          }
          ((short*)outv)[(size_t)b * outBatchStride + (size_t)t * outLD + co] = f2bf(v);
        }
      } else {
        if (co < M) {
          float v = acc[g][r] + bias[co];
          if (RELU) v = v > 0.f ? v : 0.f;
          ((float*)outv)[(size_t)b * outBatchStride + (size_t)co * outLD + t] = v;
        }
      }
    }
  }
}

// ---------------------------------------------------------------------------
// Norms: q2n[b][2048] from qA rows, k2n[b][448] from kB rows.
// 4 lanes per row (24 bf16 each), shfl-4 reduce. Padded cols are zero.
// ---------------------------------------------------------------------------
__global__ __launch_bounds__(256) void norms_kernel(
    const short* __restrict__ qA, const short* __restrict__ kB,
    float* __restrict__ q2n, float* __restrict__ k2n) {
  const int tid = threadIdx.x;
  const int R = blockIdx.x * 64 + (tid >> 2);
  const int g = tid & 3;
  const short* src;
  float* dst;
  if (R < NB * TQP) {
    src = qA + (size_t)R * 96 + g * 24;
    dst = q2n + R;
  } else {
    int R2 = R - NB * TQP;
    if (R2 >= NB * TPAD) return;
    src = kB + (size_t)R2 * 96 + g * 24;
    dst = k2n + R2;
  }
  float s = 0.f;
  #pragma unroll
  for (int c = 0; c < 3; ++c) {
    short8 v = *(const short8*)(src + c * 8);
    #pragma unroll
    for (int j = 0; j < 8; ++j) {
      float f = bf2f(v[j]);
      s += f * f;
    }
  }
  s += __shfl_xor(s, 1, 64);
  s += __shfl_xor(s, 2, 64);
  if (g == 0) *dst = s;
}

// ---------------------------------------------------------------------------
// FUSED attention (verbatim R17-R19)
// ---------------------------------------------------------------------------
__global__ __launch_bounds__(256) void attn_fused_kernel(
    const short* __restrict__ qA, const short* __restrict__ kB,
    const float* __restrict__ q2, const float* __restrict__ k2,
    const int* __restrict__ mask, float* __restrict__ out_attn,
    float* __restrict__ out_logp) {
  __shared__ short A_lds[3][2048];
  __shared__ short B_lds[3][2560];
  __shared__ float k2LDS[400];
  __shared__ int mLDS[400];
  const int t0 = blockIdx.x * 64;
  const int b  = blockIdx.y;
  const int tid = threadIdx.x;
  const int l = tid & 63, w = tid >> 6;

  {
    const int arow_s = tid >> 2, aslot = tid & 3;
    const short* gA = qA + ((size_t)b * TQP + t0 + arow_s) * 96 + aslot * 8;
    #pragma unroll
    for (int p = 0; p < 3; ++p) {
      uint4 v = *(const uint4*)(gA + p * 32);
      *(uint4*)((char*)&A_lds[p][0] +
                ((arow_s * 64 + aslot * 16) ^ ((arow_s & 7) << 4))) = v;
    }
  }
  for (int idx = tid; idx < 400; idx += 256) {
    k2LDS[idx] = k2[(size_t)b * TPAD + idx];
    mLDS[idx] = mask[(size_t)b * TEN + idx];
  }

  const int kslot = l >> 4;
  const int arow = w * 16 + (l & 15);
  const int abyte = (arow * 64 + kslot * 16) ^ ((arow & 7) << 4);

  f32x4 acc[25];
  #pragma unroll
  for (int i = 0; i < 25; ++i) acc[i] = (f32x4){0.f, 0.f, 0.f, 0.f};

  __syncthreads();
  #pragma unroll
  for (int st = 0; st < 5; ++st) {
    for (int idx = tid; idx < 960; idx += 256) {
      int row = idx / 12, c = idx - row * 12;
      int panel = c >> 2, ps = c & 3;
      uint4 v = *(const uint4*)(kB + ((size_t)b * TPAD + st * 80 + row) * 96 + c * 8);
      *(uint4*)((char*)&B_lds[panel][0] +
                ((row * 64 + ps * 16) ^ ((row & 7) << 4))) = v;
    }
    __syncthreads();
    #pragma unroll
    for (int kt = 0; kt < 3; ++kt) {
      short8 a = *(const short8*)((const char*)&A_lds[kt][0] + abyte);
      #pragma unroll
      for (int f = 0; f < 5; ++f) {
        int brow = f * 16 + (l & 15);
        short8 bb = *(const short8*)((const char*)&B_lds[kt][0] +
                                     ((brow * 64 + kslot * 16) ^ ((brow & 7) << 4)));
        acc[st * 5 + f] =
            __builtin_amdgcn_mfma_f32_16x16x32_bf16(a, bb, acc[st * 5 + f], 0, 0, 0);
      }
    }
    __syncthreads();
  }

  int trow[4]; float q2v[4];
  #pragma unroll
  for (int r = 0; r < 4; ++r) {
    trow[r] = t0 + w * 16 + kslot * 4 + r;
    q2v[r] = q2[(size_t)b * TQP + trow[r]];
  }
  #pragma unroll
  for (int sf = 0; sf < 25; ++sf) {
    int s = sf * 16 + (l & 15);
    float k2v = k2LDS[s];
    bool mk = mLDS[s] != 0;
    #pragma unroll
    for (int r = 0; r < 4; ++r) {
      float lp = mk ? (-TEMP) * (q2v[r] + k2v - 2.f * acc[sf][r]) : -INFINITY;
      acc[sf][r] = lp;
    }
  }
  #pragma unroll
  for (int r = 0; r < 4; ++r) {
    if (trow[r] < TDE) {
      float* dst = out_logp + ((size_t)(b * TDE + trow[r])) * TEN + (l & 15);
      #pragma unroll
      for (int sf = 0; sf < 25; ++sf) dst[sf * 16] = acc[sf][r];
    }
  }
  float m[4];
  #pragma unroll
  for (int r = 0; r < 4; ++r) m[r] = -INFINITY;
  #pragma unroll
  for (int sf = 0; sf < 25; ++sf)
    #pragma unroll
    for (int r = 0; r < 4; ++r) m[r] = fmaxf(m[r], acc[sf][r]);
  #pragma unroll
  for (int o = 1; o < 16; o <<= 1)
    #pragma unroll
    for (int r = 0; r < 4; ++r) m[r] = fmaxf(m[r], __shfl_xor(m[r], o, 64));
  float sum[4] = {0.f, 0.f, 0.f, 0.f};
  #pragma unroll
  for (int sf = 0; sf < 25; ++sf)
    #pragma unroll
    for (int r = 0; r < 4; ++r) {
      float v = acc[sf][r];
      float e = (v != -INFINITY) ? __expf(v - m[r]) : 0.f;
      acc[sf][r] = e;
      sum[r] += e;
    }
  #pragma unroll
  for (int o = 1; o < 16; o <<= 1)
    #pragma unroll
    for (int r = 0; r < 4; ++r) sum[r] += __shfl_xor(sum[r], o, 64);
  float inv[4];
  #pragma unroll
  for (int r = 0; r < 4; ++r) inv[r] = 1.0f / sum[r];
  #pragma unroll
  for (int r = 0; r < 4; ++r) {
    if (trow[r] < TDE) {
      float* dst = out_attn + ((size_t)(b * TDE + trow[r])) * TEN + (l & 15);
      #pragma unroll
      for (int sf = 0; sf < 25; ++sf) dst[sf * 16] = acc[sf][r] * inv[r];
    }
  }
}

extern "C" void kernel_launch(void* const* d_in, const int* in_sizes, int n_in,
                              void* d_out, int out_size, void* d_ws, size_t ws_size,
                              hipStream_t stream) {
  const float* queries = (const float*)d_in[0];
  const float* keys    = (const float*)d_in[1];
  const int*   mask    = (const int*)d_in[2];
  const float* kw1 = (const float*)d_in[3];
  const float* kb1 = (const float*)d_in[4];
  const float* kw2 = (const float*)d_in[5];
  const float* kb2 = (const float*)d_in[6];
  const float* qw1 = (const float*)d_in[7];
  const float* qb1 = (const float*)d_in[8];
  const float* qw2 = (const float*)d_in[9];
  const float* qb2 = (const float*)d_in[10];
  const float* qw3 = (const float*)d_in[11];
  const float* qb3 = (const float*)d_in[12];
  float* out = (float*)d_out;

  char* ws = (char*)d_ws;
  // ws overlays (stream-ordered):
  //  K: BmatT [0,44.04M) | w1bf [44.04M,47.19M) | k1t [47.19M,76.55M) |
  //     w2bf [76.55M,76.81M) | wq [76.81M,76.97M) | kB [81.92M,84.67M)
  //  Q: Bq [0,33.55M) | q1bf [33.55M,54.53M) | q2bf [54.53M,67.11M)
  //  A: qA [20.48M,33.06M) (dead Bq) | q2n [33.06M,33.33M) (dead Bq) |
  //     k2n [49.94M,50.00M) (dead q1bf)
  short* BmatT = (short*)ws;
  short* w1bf  = (short*)(ws + 44040192);
  short* k1t   = (short*)(ws + 47185920);
  short* w2bf  = (short*)(ws + 76546048);
  short* w1q   = (short*)(ws + 76808192);
  short* w2q   = (short*)(ws + 76906496);
  short* w3q   = (short*)(ws + 76947456);
  short* Bq    = (short*)ws;
  short* q1bf  = (short*)(ws + 33554432);
  short* q2bf  = (short*)(ws + 54525952);
  short* qA    = (short*)(ws + 20480000);
  float* q2n   = (float*)(ws + 33062912);
  float* k2n   = (float*)(ws + 49938432);
  short* kB    = (short*)(ws + 81920000);

  const long long HALF = 25600000LL;
  float* out_attn = out;
  float* out_logp = out + HALF;

  // --- weights (one fused launch) ---
  cvt_weights_kernel<<<dim3(6976), dim3(256), 0, stream>>>(
      kw1, kw2, qw1, qw2, qw3, w1bf, w2bf, w1q, w2q, w3q);

  // --- key path ---
  im2col_kernel<<<dim3(TEN, NB), dim3(256), 0, stream>>>(keys, BmatT);
  kconv1_mfma_kernel<<<dim3(1024), dim3(256), 0, stream>>>(w1bf, BmatT, kb1, k1t);
  qgemm_kernel<1, false><<<dim3(2, 7, NB), dim3(256), 0, stream>>>(
      w2bf, k1t, kb2, kB, CA, C1, 32, TEN, 96,
      (size_t)TPAD * C1, (size_t)TPAD * 96, 96);

  // --- query path (MFMA chain -> qA bf16 directly) ---
  im2col_q_kernel<<<dim3(TQP, NB), dim3(256), 0, stream>>>(queries, Bq);
  qgemm_kernel<1, true><<<dim3(3, TQP / 64, NB), dim3(256), 0, stream>>>(
      w1q, Bq, qb1, q1bf, CQ2, 256, 8, TQP, 160,
      (size_t)TQP * 256, (size_t)TQP * 160, 160);
  qgemm_kernel<1, true><<<dim3(2, TQP / 64, NB), dim3(256), 0, stream>>>(
      w2q, q1bf, qb2, q2bf, CA, 160, 5, TQP, 96,
      (size_t)TQP * 160, (size_t)TQP * 96, 96);
  qgemm_kernel<1, false><<<dim3(2, TQP / 64, NB), dim3(256), 0, stream>>>(
      w3q, q2bf, qb3, qA, CA, 96, 3, TQP, 96,
      (size_t)TQP * 96, (size_t)TQP * 96, 96);

  // --- norms + fused attention ---
  norms_kernel<<<dim3((NB * TQP + NB * TPAD) / 64), dim3(256), 0, stream>>>(
      qA, kB, q2n, k2n);
  attn_fused_kernel<<<dim3(TQP / 64, NB), dim3(256), 0, stream>>>(
      qA, kB, q2n, k2n, mask, out_attn, out_logp);
}